// Round 4
// baseline (3306.032 us; speedup 1.0000x reference)
//
#include <hip/hip_runtime.h>
#include <math.h>

#define B 32
#define V 16
#define T 64
#define F 64
#define H 512
#define NB 36
#define G4H 2048

typedef unsigned short u16;
typedef __attribute__((ext_vector_type(8))) short bf16x8;
typedef __attribute__((ext_vector_type(4))) float f32x4;

// workspace offsets (float units)
#define OFF_H0     0           // 262144
#define OFF_H1     262144      // 262144
#define OFF_C      524288      // 262144
#define OFF_CNT    786432      // 64 (barrier counters; zeroed with h/c in one k_zero)
#define OFF_WALL   786496      // 524288 fp32 w_all; ctx/hsoft alias (dead after k_recur)
#define OFF_CTX    786496      // 262144 (alias)
#define OFF_HSOFT  1048640     // 262144 (alias)
#define OFF_WMAX   1310784     // 64
#define OFF_WHSTG  1310848     // 131072 fl = 262144 u16 (wh, A-frag bf16)
#define OFF_SEQSTG 1441920     // 1064960 fl = 2129920 u16 (seq all t + denorm t=64, A-frag)
#define OFF_WSTG   2506880     // 9437184 fl (weights, B-frag bf16)
#define OFF_ENC    11944064    // 8388608 fl = 16777216 u16 (enc bf16)
// total 20,332,672 fl = 81.3 MB

__device__ __forceinline__ float sigmoidf_(float x) { return 1.0f / (1.0f + __expf(-x)); }

__device__ __forceinline__ u16 f2bf(float f) {  // RNE fp32->bf16
    union { float f; unsigned u; } x; x.f = f;
    unsigned r = x.u + 0x7FFF + ((x.u >> 16) & 1);
    return (u16)(r >> 16);
}
__device__ __forceinline__ float bf2f(u16 u) {
    union { unsigned i; float f; } x; x.i = ((unsigned)u) << 16;
    return x.f;
}
__device__ __forceinline__ f32x4 mfma16(bf16x8 a, bf16x8 b, f32x4 c) {
    return __builtin_amdgcn_mfma_f32_16x16x32_bf16(a, b, c, 0, 0, 0);
}

// device-scope barrier: monotone counter, relaxed poll, fences at edges.
__device__ __forceinline__ void sync_across(unsigned* cnt, unsigned target) {
    __syncthreads();
    if (threadIdx.x == 0) {
        __threadfence();  // release: publish this block's writes
        __hip_atomic_fetch_add(cnt, 1u, __ATOMIC_RELAXED, __HIP_MEMORY_SCOPE_AGENT);
        while (__hip_atomic_load(cnt, __ATOMIC_RELAXED, __HIP_MEMORY_SCOPE_AGENT) < target)
            __builtin_amdgcn_s_sleep(1);
        __threadfence();  // acquire: invalidate stale cached lines
    }
    __syncthreads();
}

// ---------------------------------------------------------------------------
__global__ void k_zero(float* __restrict__ p, int n) {
    int i = blockIdx.x * blockDim.x + threadIdx.x;
    if (i < n) p[i] = 0.0f;
}

// ---------------------------------------------------------------------------
// hardwired weights for all t: w_all[t][b][i][j] fp32 + wmax_all[t]
__global__ __launch_bounds__(256) void k_hw_all(
    const float* __restrict__ dist, const int* __restrict__ rb,
    const int* __restrict__ cog, const float* __restrict__ mask,
    const float* __restrict__ domain, float* __restrict__ w_all,
    float* __restrict__ wmax_all) {
    int t = blockIdx.x;
    __shared__ float red[256];
    int tid = threadIdx.x;
    float lmax = 0.0f;
    for (int idx = tid; idx < B * V * V; idx += 256) {
        int b = idx >> 8;
        int rem = idx & 255;
        int i = rem >> 4, j = rem & 15;
        int base = ((b * V + i) * T + t) * V + j;
        float val = domain[cog[base] * NB + rb[base]] - dist[base];
        val = val > 0.0f ? val : 0.0f;
        val *= mask[(b * V + i) * T + t] * mask[(b * V + j) * T + t];
        w_all[t * (B * V * V) + idx] = val;
        lmax = fmaxf(lmax, val);
    }
    red[tid] = lmax;
    __syncthreads();
    for (int s = 128; s > 0; s >>= 1) {
        if (tid < s) red[tid] = fmaxf(red[tid], red[tid + s]);
        __syncthreads();
    }
    if (tid == 0) wmax_all[t] = red[0];
}

// ---------------------------------------------------------------------------
// One-time: W_ih||W_hh (fp32, K-minor) -> bf16 B-fragment layout
// Wstg[v][hk16][ks18][nt8][lane64][8]; nt=g*2+hh; col=g*512+hk*32+hh*16+(lane&15)
__global__ __launch_bounds__(256) void k_wconv(
    const float* __restrict__ W_ih, const float* __restrict__ W_hh,
    u16* __restrict__ Wstg) {
    int v = blockIdx.x, hk = blockIdx.y, ks = blockIdx.z;
    int tid = threadIdx.x;
#pragma unroll
    for (int s = 0; s < 2; ++s) {
        int slot = tid + s * 256;
        int nt = slot >> 6, lane = slot & 63;
        int g = nt >> 1, hh = nt & 1;
        int col = g * H + hk * 32 + hh * 16 + (lane & 15);
        int k = ks * 32 + ((lane >> 4) << 3);
        const float* src = (k < F) ? &W_ih[(v * G4H + col) * F + k]
                                   : &W_hh[(v * G4H + col) * H + (k - F)];
        float4 x0 = *(const float4*)src;
        float4 x1 = *(const float4*)(src + 4);
        union { u16 u[8]; uint4 q; } pk;
        pk.u[0] = f2bf(x0.x); pk.u[1] = f2bf(x0.y); pk.u[2] = f2bf(x0.z); pk.u[3] = f2bf(x0.w);
        pk.u[4] = f2bf(x1.x); pk.u[5] = f2bf(x1.y); pk.u[6] = f2bf(x1.z); pk.u[7] = f2bf(x1.w);
        *(uint4*)&Wstg[(size_t)((((v * 16 + hk) * 18 + ks) * 8 + nt) * 64 + lane) * 8] = pk.q;
    }
}

// ---------------------------------------------------------------------------
// One-time: pack seq for all t (t=64 = denormalized last input) into A-frag bf16:
// seqstg[t][v][mt2][ks2][lane64][8]
__global__ __launch_bounds__(256) void k_seqstg(
    const float* __restrict__ seq, const float* __restrict__ maxval,
    const float* __restrict__ minval, u16* __restrict__ seqstg) {
    int v = blockIdx.x, t = blockIdx.y;  // t in 0..64
    int tid = threadIdx.x;
    int mt = tid >> 7, ks = (tid >> 6) & 1, lane = tid & 63;
    int b = mt * 16 + (lane & 15);
    int f = ks * 32 + ((lane >> 4) << 3);
    union { u16 u[8]; uint4 q; } pk;
    if (t < T) {
        const float* sp = &seq[((b * V + v) * T + t) * F + f];
        float4 x0 = *(const float4*)sp, x1 = *(const float4*)(sp + 4);
        pk.u[0] = f2bf(x0.x); pk.u[1] = f2bf(x0.y); pk.u[2] = f2bf(x0.z); pk.u[3] = f2bf(x0.w);
        pk.u[4] = f2bf(x1.x); pk.u[5] = f2bf(x1.y); pk.u[6] = f2bf(x1.z); pk.u[7] = f2bf(x1.w);
    } else {
        const float* sp = &seq[((b * V + v) * T + (T - 1)) * F + f];
        float4 x0 = *(const float4*)sp, x1 = *(const float4*)(sp + 4);
        float4 mx0 = *(const float4*)&maxval[b * F + f], mx1 = *(const float4*)&maxval[b * F + f + 4];
        float4 mn0 = *(const float4*)&minval[b * F + f], mn1 = *(const float4*)&minval[b * F + f + 4];
        pk.u[0] = f2bf(x0.x * (mx0.x - mn0.x) + mn0.x);
        pk.u[1] = f2bf(x0.y * (mx0.y - mn0.y) + mn0.y);
        pk.u[2] = f2bf(x0.z * (mx0.z - mn0.z) + mn0.z);
        pk.u[3] = f2bf(x0.w * (mx0.w - mn0.w) + mn0.w);
        pk.u[4] = f2bf(x1.x * (mx1.x - mn1.x) + mn1.x);
        pk.u[5] = f2bf(x1.y * (mx1.y - mn1.y) + mn1.y);
        pk.u[6] = f2bf(x1.z * (mx1.z - mn1.z) + mn1.z);
        pk.u[7] = f2bf(x1.w * (mx1.w - mn1.w) + mn1.w);
    }
    *(uint4*)&seqstg[(((size_t)(t * 16 + v)) * 4 + mt * 2 + ks) * 512 + lane * 8] = pk.q;
}

// ---------------------------------------------------------------------------
// Persistent recurrence: 65 steps in one launch.  256 blocks x 256 threads.
// block: v = bid&15, hk = bid>>4 (phase A: hk doubles as the ks chunk index).
// Per step: A (wh from h) -> vessel barrier(16) -> B (MFMA gates + update) -> grid barrier.
// h double-buffered: A(t) reads hbuf[(t+1)&1], B(t) writes hbuf[t&1].
__global__ __launch_bounds__(256) void k_recur(
    const u16* __restrict__ seqstg, const u16* __restrict__ Wstg,
    const float* __restrict__ w_all, const float* __restrict__ wmax_all,
    const float* __restrict__ b_ih, const float* __restrict__ b_hh,
    float* __restrict__ h0buf, float* __restrict__ h1buf,
    float* __restrict__ c, u16* __restrict__ enc, u16* __restrict__ whstg,
    unsigned* __restrict__ bar) {
    int bid = blockIdx.x;
    int v = bid & 15, hk = bid >> 4;
    int tid = threadIdx.x;
    __shared__ u16 Abuf[36 * 512];     // 36 KB
    __shared__ u16 Wbuf[2][8 * 512];   // 16 KB
    __shared__ float sw[32][16];       // 2 KB  (w rows for this v)

    const u16* wks = Wstg + (size_t)((v * 16 + hk) * 18) * 4096;

    int lane = tid & 63, wv = tid >> 6;
    int mtw = wv & 1, hh = wv >> 1;
    int col = hk * 32 + hh * 16 + (lane & 15);
    int q4 = (lane >> 4) << 2;
    float bi = b_ih[v * G4H + col] + b_hh[v * G4H + col];
    float bf_ = b_ih[v * G4H + H + col] + b_hh[v * G4H + H + col];
    float bg_ = b_ih[v * G4H + 2 * H + col] + b_hh[v * G4H + 2 * H + col];
    float bo = b_ih[v * G4H + 3 * H + col] + b_hh[v * G4H + 3 * H + col];

    unsigned* gcnt = bar;
    unsigned* vcnt = bar + 1 + v;
    unsigned gtarget = 0, vtarget = 0;

    // phase-A constants (threads 0..127 active)
    int amt = tid >> 6;
    int as6 = tid & 63;
    int ab = amt * 16 + (as6 & 15);
    int akhid = hk * 32 + (as6 >> 4) * 8;

    for (int t = 0; t <= T; ++t) {
        int tm = t < T ? t : (T - 1);
        const float* hin = (t & 1) ? h0buf : h1buf;
        float* hout = (t & 1) ? h1buf : h0buf;

        // stage seq chunks (ks 0,1 per mt) into Abuf; prefetch W ks=0 into regs
        {
            int ch = tid >> 6;  // 0..3
            int mt2 = ch >> 1, ks2 = ch & 1;
            uint4 sv = *(const uint4*)&seqstg[(((size_t)(t * 16 + v)) * 4 + mt2 * 2 + ks2) * 512 + lane * 8];
            *(uint4*)&Abuf[(mt2 * 18 + ks2) * 512 + lane * 8] = sv;
        }
        uint4 wa = *(const uint4*)&wks[tid * 8];
        uint4 wb = *(const uint4*)&wks[(tid + 256) * 8];

        // phase A: wh chunk (v, amt, ks=hk) from hin
        for (int i = tid; i < 512; i += 256)
            sw[i >> 4][i & 15] = w_all[((size_t)tm * (B * V) + (i >> 4) * V + v) * V + (i & 15)];
        __syncthreads();
        if (tid < 128) {
            float inv = 1.0f / wmax_all[tm];
            float a0 = 0, a1 = 0, a2 = 0, a3 = 0, a4 = 0, a5 = 0, a6 = 0, a7 = 0;
#pragma unroll
            for (int j = 0; j < 16; ++j) {
                const float* hp = &hin[(ab * V + j) * H + akhid];
                float4 x0 = *(const float4*)hp;
                float4 x1 = *(const float4*)(hp + 4);
                float wj = sw[ab][j];
                a0 += wj * x0.x; a1 += wj * x0.y; a2 += wj * x0.z; a3 += wj * x0.w;
                a4 += wj * x1.x; a5 += wj * x1.y; a6 += wj * x1.z; a7 += wj * x1.w;
            }
            union { u16 u[8]; uint4 q; } pk;
            pk.u[0] = f2bf(a0 * inv); pk.u[1] = f2bf(a1 * inv);
            pk.u[2] = f2bf(a2 * inv); pk.u[3] = f2bf(a3 * inv);
            pk.u[4] = f2bf(a4 * inv); pk.u[5] = f2bf(a5 * inv);
            pk.u[6] = f2bf(a6 * inv); pk.u[7] = f2bf(a7 * inv);
            *(uint4*)&whstg[(((v * 2 + amt) * 16 + hk) * 64 + as6) * 8] = pk.q;
        }

        // vessel barrier: the 16 blocks sharing v
        vtarget += 16;
        sync_across(vcnt, vtarget);

        // stage wh chunks (ks 2..17 per mt) into Abuf
#pragma unroll
        for (int i = 0; i < 8; ++i) {
            int task = tid + i * 256;
            int ch = task >> 6, ln = task & 63;
            int mt2 = ch >> 4, ksw = ch & 15;
            *(uint4*)&Abuf[(mt2 * 18 + 2 + ksw) * 512 + ln * 8] =
                *(const uint4*)&whstg[(((v * 2 + mt2) * 16 + ksw) * 64 + ln) * 8];
        }
        *(uint4*)&Wbuf[0][tid * 8] = wa;
        *(uint4*)&Wbuf[0][(tid + 256) * 8] = wb;
        wa = *(const uint4*)&wks[4096 + tid * 8];
        wb = *(const uint4*)&wks[4096 + (tid + 256) * 8];
        __syncthreads();

        f32x4 acc[4];
#pragma unroll
        for (int g = 0; g < 4; ++g) { acc[g][0] = 0.f; acc[g][1] = 0.f; acc[g][2] = 0.f; acc[g][3] = 0.f; }

        for (int ks = 0; ks < 18; ++ks) {
            int cur = ks & 1;
            bf16x8 af = *(const bf16x8*)&Abuf[(mtw * 18 + ks) * 512 + lane * 8];
#pragma unroll
            for (int g = 0; g < 4; ++g) {
                bf16x8 bfr = *(const bf16x8*)&Wbuf[cur][((g << 1) + hh) * 512 + lane * 8];
                acc[g] = mfma16(af, bfr, acc[g]);
            }
            if (ks < 17) {
                *(uint4*)&Wbuf[cur ^ 1][tid * 8] = wa;
                *(uint4*)&Wbuf[cur ^ 1][(tid + 256) * 8] = wb;
                if (ks < 16) {
                    wa = *(const uint4*)&wks[(size_t)(ks + 2) * 4096 + tid * 8];
                    wb = *(const uint4*)&wks[(size_t)(ks + 2) * 4096 + (tid + 256) * 8];
                }
                __syncthreads();
            }
        }

        // epilogue: c/h update (thread-private c slice), enc store
#pragma unroll
        for (int r = 0; r < 4; ++r) {
            int b = mtw * 16 + q4 + r;
            float gi = acc[0][r] + bi;
            float gf = acc[1][r] + bf_;
            float gg = acc[2][r] + bg_;
            float go = acc[3][r] + bo;
            int idx = (b * V + v) * H + col;
            float cn = sigmoidf_(gf) * c[idx] + sigmoidf_(gi) * tanhf(gg);
            float hn = sigmoidf_(go) * tanhf(cn);
            c[idx] = cn;
            hout[idx] = hn;
            if (t < T) enc[((size_t)(b * V + v) * T + t) * H + col] = f2bf(hn);
        }

        if (t < T) {  // publish h for next step's phase A
            gtarget += 256;
            sync_across(gcnt, gtarget);
        }
    }
}

// ---------------------------------------------------------------------------
// soft attention over bf16 enc.  block=(b,v)
__global__ __launch_bounds__(256) void k_attn(
    const u16* __restrict__ enc, const float* __restrict__ h,
    const float* __restrict__ mask, float* __restrict__ ctx) {
    int bid = blockIdx.x;
    int b = bid >> 4, v = bid & 15;
    int tid = threadIdx.x;
    int wave = tid >> 6, lane = tid & 63;
    __shared__ float hs[H];
    __shared__ float sc[T];
    __shared__ float al[T];
    const u16* encbase = enc + (size_t)((b * V + v) * T) * H;
    const float* hb = h + (b * V + v) * H;
    for (int i = tid; i < H; i += 256) hs[i] = hb[i];
    __syncthreads();
    for (int tt = wave; tt < T; tt += 4) {
        const u16* e = encbase + tt * H;
        float p = 0.0f;
#pragma unroll
        for (int ii = 0; ii < 8; ++ii) p += bf2f(e[ii * 64 + lane]) * hs[ii * 64 + lane];
        for (int off = 32; off; off >>= 1) p += __shfl_down(p, off, 64);
        if (lane == 0) sc[tt] = p;
    }
    __syncthreads();
    if (tid < 64) {
        float m_t = mask[(b * V + v) * T + tid];
        float s = sc[tid] * m_t;
        float mx = s;
        for (int off = 32; off; off >>= 1) mx = fmaxf(mx, __shfl_xor(mx, off, 64));
        float e = __expf(s - mx);
        float sum = e;
        for (int off = 32; off; off >>= 1) sum += __shfl_xor(sum, off, 64);
        al[tid] = e / sum;
    }
    __syncthreads();
    for (int hh = tid; hh < H; hh += 256) {
        float a = 0.0f;
        for (int tt = 0; tt < T; ++tt) a += al[tt] * bf2f(encbase[tt * H + hh]);
        ctx[(b * V + v) * H + hh] = a;
    }
}

// ---------------------------------------------------------------------------
// per-vessel soft linear (torch stack/view reinterleave).  grid (16,16), 32-col tiles.
__global__ __launch_bounds__(256) void k_soft(
    const float* __restrict__ ctx, const float* __restrict__ hdec,
    const float* __restrict__ soft_W, const float* __restrict__ soft_b,
    float* __restrict__ hsoft) {
    int v = blockIdx.x;
    int h0 = blockIdx.y * 32;
    int tid = threadIdx.x;
    int cg = tid & 31, rg = tid >> 5;
    __shared__ float sA[32][36];
    __shared__ float sW2[32][36];
    float* sAf = &sA[0][0];
    float* sWf = &sW2[0][0];
    float acc[4] = {0.f, 0.f, 0.f, 0.f};
    int arow = tid >> 3, akq = tid & 7;
    float4 areg, wreg;

    {
        int k = akq * 4;
        const float* src = (arow < 16) ? ctx : hdec;
        int bsrc = 2 * (arow & 15) + (k >= H ? 1 : 0);
        areg = *(const float4*)&src[(bsrc * V + v) * H + (k & (H - 1))];
        wreg = *(const float4*)&soft_W[(v * H + h0 + arow) * (2 * H) + k];
    }
    for (int kc = 0; kc < 2 * H; kc += 32) {
        __syncthreads();
        *(float4*)&sAf[arow * 36 + akq * 4] = areg;
        *(float4*)&sWf[arow * 36 + akq * 4] = wreg;
        __syncthreads();
        if (kc + 32 < 2 * H) {
            int k = kc + 32 + akq * 4;
            const float* src = (arow < 16) ? ctx : hdec;
            int bsrc = 2 * (arow & 15) + (k >= H ? 1 : 0);
            areg = *(const float4*)&src[(bsrc * V + v) * H + (k & (H - 1))];
            wreg = *(const float4*)&soft_W[(v * H + h0 + arow) * (2 * H) + kc + 32 + akq * 4];
        }
#pragma unroll
        for (int k4 = 0; k4 < 8; ++k4) {
            float4 wv = *(const float4*)&sWf[cg * 36 + k4 * 4];
            float4 a0 = *(const float4*)&sAf[(rg * 4 + 0) * 36 + k4 * 4];
            float4 a1 = *(const float4*)&sAf[(rg * 4 + 1) * 36 + k4 * 4];
            float4 a2 = *(const float4*)&sAf[(rg * 4 + 2) * 36 + k4 * 4];
            float4 a3 = *(const float4*)&sAf[(rg * 4 + 3) * 36 + k4 * 4];
            acc[0] += a0.x * wv.x + a0.y * wv.y + a0.z * wv.z + a0.w * wv.w;
            acc[1] += a1.x * wv.x + a1.y * wv.y + a1.z * wv.z + a1.w * wv.w;
            acc[2] += a2.x * wv.x + a2.y * wv.y + a2.z * wv.z + a2.w * wv.w;
            acc[3] += a3.x * wv.x + a3.y * wv.y + a3.z * wv.z + a3.w * wv.w;
        }
    }
    float bb = soft_b[v * H + h0 + cg];
#pragma unroll
    for (int r = 0; r < 4; ++r) {
        int row = rg * 4 + r;
        hsoft[(row * V + v) * H + h0 + cg] = tanhf(acc[r] + bb);
    }
}

// ---------------------------------------------------------------------------
__global__ __launch_bounds__(64) void k_out(
    const float* __restrict__ hsoft, const float* __restrict__ outW,
    const float* __restrict__ outb, float* __restrict__ out) {
    int bid = blockIdx.x;
    int b = bid >> 4, v = bid & 15;
    int lane = threadIdx.x;
    const float* hb = hsoft + (b * V + v) * H;
    float p[4] = {0.0f, 0.0f, 0.0f, 0.0f};
#pragma unroll
    for (int ii = 0; ii < 8; ++ii) {
        float hv = hb[ii * 64 + lane];
#pragma unroll
        for (int o = 0; o < 4; ++o) p[o] += hv * outW[o * H + ii * 64 + lane];
    }
#pragma unroll
    for (int o = 0; o < 4; ++o) {
        float s = p[o];
        for (int off = 32; off; off >>= 1) s += __shfl_down(s, off, 64);
        if (lane == 0) {
            float val = s + outb[o];
            out[(b * V + v) * 4 + o] = val > 0.0f ? val : 0.0f;
        }
    }
}

// ---------------------------------------------------------------------------
extern "C" void kernel_launch(void* const* d_in, const int* in_sizes, int n_in,
                              void* d_out, int out_size, void* d_ws, size_t ws_size,
                              hipStream_t stream) {
    const float* seq = (const float*)d_in[0];
    const float* dist = (const float*)d_in[1];
    const int* rb = (const int*)d_in[2];
    const int* cog = (const int*)d_in[3];
    const float* mask = (const float*)d_in[4];
    const float* maxval = (const float*)d_in[5];
    const float* minval = (const float*)d_in[6];
    const float* W_ih = (const float*)d_in[7];
    const float* W_hh = (const float*)d_in[8];
    const float* b_ih = (const float*)d_in[9];
    const float* b_hh = (const float*)d_in[10];
    const float* domain = (const float*)d_in[11];
    const float* soft_W = (const float*)d_in[12];
    const float* soft_b = (const float*)d_in[13];
    const float* out_W = (const float*)d_in[14];
    const float* out_b = (const float*)d_in[15];

    float* ws = (float*)d_ws;
    float* h0buf = ws + OFF_H0;
    float* h1buf = ws + OFF_H1;
    float* c = ws + OFF_C;
    unsigned* bar = (unsigned*)(ws + OFF_CNT);
    float* w_all = ws + OFF_WALL;
    float* ctx = ws + OFF_CTX;      // alias (w_all dead after k_recur)
    float* hsoft = ws + OFF_HSOFT;  // alias
    float* wmax_all = ws + OFF_WMAX;
    u16* whstg = (u16*)(ws + OFF_WHSTG);
    u16* seqstg = (u16*)(ws + OFF_SEQSTG);
    u16* Wstg = (u16*)(ws + OFF_WSTG);
    u16* enc = (u16*)(ws + OFF_ENC);

    // zero h0,h1,c + barrier counters (contiguous [0, 786496))
    k_zero<<<3073, 256, 0, stream>>>(ws, 786496);
    k_hw_all<<<T, 256, 0, stream>>>(dist, rb, cog, mask, domain, w_all, wmax_all);
    k_wconv<<<dim3(16, 16, 18), 256, 0, stream>>>(W_ih, W_hh, Wstg);
    k_seqstg<<<dim3(16, T + 1), 256, 0, stream>>>(seq, maxval, minval, seqstg);

    // whole recurrence (64 encoder steps + 1 decoder step) in one launch
    k_recur<<<256, 256, 0, stream>>>(seqstg, Wstg, w_all, wmax_all, b_ih, b_hh,
                                     h0buf, h1buf, c, enc, whstg, bar);

    // final h is in h0buf (t=64 writes buf[0])
    k_attn<<<B * V, 256, 0, stream>>>(enc, h0buf, mask, ctx);
    k_soft<<<dim3(16, 16), 256, 0, stream>>>(ctx, h0buf, soft_W, soft_b, hsoft);
    k_out<<<B * V, 64, 0, stream>>>(hsoft, out_W, out_b, (float*)d_out);
}

// Round 5
// 1293.072 us; speedup vs baseline: 2.5567x; 2.5567x over previous
//
#include <hip/hip_runtime.h>
#include <math.h>

#define B 32
#define V 16
#define T 64
#define F 64
#define H 512
#define NB 36
#define G4H 2048

typedef unsigned short u16;
typedef unsigned long long ull;
typedef __attribute__((ext_vector_type(8))) short bf16x8;
typedef __attribute__((ext_vector_type(4))) float f32x4;

// workspace offsets (float units)
#define OFF_H0     0           // 262144
#define OFF_H1     262144      // 262144
#define OFF_C      524288      // 262144
#define OFF_CNT    786432      // 512 (32 barrier counters, 64B-padded)
#define OFF_WALL   786944      // 524288 fp32 w_all; ctx/hsoft alias (dead after k_recur)
#define OFF_CTX    786944      // 262144 (alias)
#define OFF_HSOFT  1049088     // 262144 (alias)
#define OFF_WMAX   1311232     // 64
#define OFF_WHSTG  1311296     // 262144 fl = 2 parities x 262144 u16 (wh, A-frag bf16)
#define OFF_SEQSTG 1573440     // 1064960 fl = 2129920 u16 (seq all t + denorm t=64, A-frag)
#define OFF_WSTG   2638400     // 9437184 fl (weights, B-frag bf16)
#define OFF_ENC    12075584    // 8388608 fl = 16777216 u16 (enc bf16)
// total 20,464,192 fl = 81.9 MB (ws poison fill shows ~268 MB available)

#define WHP 262144   // u16 per whstg parity

__device__ __forceinline__ float sigmoidf_(float x) { return 1.0f / (1.0f + __expf(-x)); }

__device__ __forceinline__ u16 f2bf(float f) {  // RNE fp32->bf16
    union { float f; unsigned u; } x; x.f = f;
    unsigned r = x.u + 0x7FFF + ((x.u >> 16) & 1);
    return (u16)(r >> 16);
}
__device__ __forceinline__ float bf2f(u16 u) {
    union { unsigned i; float f; } x; x.i = ((unsigned)u) << 16;
    return x.f;
}
__device__ __forceinline__ f32x4 mfma16(bf16x8 a, bf16x8 b, f32x4 c) {
    return __builtin_amdgcn_mfma_f32_16x16x32_bf16(a, b, c, 0, 0, 0);
}

// device-scope coherent accesses (bypass non-coherent L1/L2; no fence needed)
__device__ __forceinline__ ull ld_agent(const ull* p) {
    return __hip_atomic_load((ull*)p, __ATOMIC_RELAXED, __HIP_MEMORY_SCOPE_AGENT);
}
__device__ __forceinline__ void st_agent(ull* p, ull x) {
    __hip_atomic_store(p, x, __ATOMIC_RELAXED, __HIP_MEMORY_SCOPE_AGENT);
}
__device__ __forceinline__ void st_agent_f(float* p, float x) {
    __hip_atomic_store(p, x, __ATOMIC_RELAXED, __HIP_MEMORY_SCOPE_AGENT);
}

// group barrier: relaxed monotone counter. Visibility comes from the data
// accesses themselves being device-scope (sc1); ordering from the compiler's
// s_waitcnt vmcnt(0) before s_barrier (all waves' stores drained at arrival).
__device__ __forceinline__ void bar_sync(unsigned* cnt, unsigned target) {
    __syncthreads();
    if (threadIdx.x == 0) {
        __builtin_amdgcn_s_waitcnt(0);  // belt-and-braces: this wave fully drained
        __hip_atomic_fetch_add(cnt, 1u, __ATOMIC_RELAXED, __HIP_MEMORY_SCOPE_AGENT);
        while (__hip_atomic_load(cnt, __ATOMIC_RELAXED, __HIP_MEMORY_SCOPE_AGENT) < target)
            __builtin_amdgcn_s_sleep(2);
    }
    __syncthreads();
}

// ---------------------------------------------------------------------------
__global__ void k_zero(float* __restrict__ p, int n) {
    int i = blockIdx.x * blockDim.x + threadIdx.x;
    if (i < n) p[i] = 0.0f;
}

// ---------------------------------------------------------------------------
// hardwired weights for all t: w_all[t][b][i][j] fp32 + wmax_all[t]
__global__ __launch_bounds__(256) void k_hw_all(
    const float* __restrict__ dist, const int* __restrict__ rb,
    const int* __restrict__ cog, const float* __restrict__ mask,
    const float* __restrict__ domain, float* __restrict__ w_all,
    float* __restrict__ wmax_all) {
    int t = blockIdx.x;
    __shared__ float red[256];
    int tid = threadIdx.x;
    float lmax = 0.0f;
    for (int idx = tid; idx < B * V * V; idx += 256) {
        int b = idx >> 8;
        int rem = idx & 255;
        int i = rem >> 4, j = rem & 15;
        int base = ((b * V + i) * T + t) * V + j;
        float val = domain[cog[base] * NB + rb[base]] - dist[base];
        val = val > 0.0f ? val : 0.0f;
        val *= mask[(b * V + i) * T + t] * mask[(b * V + j) * T + t];
        w_all[t * (B * V * V) + idx] = val;
        lmax = fmaxf(lmax, val);
    }
    red[tid] = lmax;
    __syncthreads();
    for (int s = 128; s > 0; s >>= 1) {
        if (tid < s) red[tid] = fmaxf(red[tid], red[tid + s]);
        __syncthreads();
    }
    if (tid == 0) wmax_all[t] = red[0];
}

// ---------------------------------------------------------------------------
// One-time: W_ih||W_hh (fp32, K-minor) -> bf16 B-fragment layout
// Wstg[v][hk16][ks18][nt8][lane64][8]; nt=g*2+hh; col=g*512+hk*32+hh*16+(lane&15)
__global__ __launch_bounds__(256) void k_wconv(
    const float* __restrict__ W_ih, const float* __restrict__ W_hh,
    u16* __restrict__ Wstg) {
    int v = blockIdx.x, hk = blockIdx.y, ks = blockIdx.z;
    int tid = threadIdx.x;
#pragma unroll
    for (int s = 0; s < 2; ++s) {
        int slot = tid + s * 256;
        int nt = slot >> 6, lane = slot & 63;
        int g = nt >> 1, hh = nt & 1;
        int col = g * H + hk * 32 + hh * 16 + (lane & 15);
        int k = ks * 32 + ((lane >> 4) << 3);
        const float* src = (k < F) ? &W_ih[(v * G4H + col) * F + k]
                                   : &W_hh[(v * G4H + col) * H + (k - F)];
        float4 x0 = *(const float4*)src;
        float4 x1 = *(const float4*)(src + 4);
        union { u16 u[8]; uint4 q; } pk;
        pk.u[0] = f2bf(x0.x); pk.u[1] = f2bf(x0.y); pk.u[2] = f2bf(x0.z); pk.u[3] = f2bf(x0.w);
        pk.u[4] = f2bf(x1.x); pk.u[5] = f2bf(x1.y); pk.u[6] = f2bf(x1.z); pk.u[7] = f2bf(x1.w);
        *(uint4*)&Wstg[(size_t)((((v * 16 + hk) * 18 + ks) * 8 + nt) * 64 + lane) * 8] = pk.q;
    }
}

// ---------------------------------------------------------------------------
// One-time: pack seq for all t (t=64 = denormalized last input) into A-frag bf16:
// seqstg[t][v][mt2][ks2][lane64][8]
__global__ __launch_bounds__(256) void k_seqstg(
    const float* __restrict__ seq, const float* __restrict__ maxval,
    const float* __restrict__ minval, u16* __restrict__ seqstg) {
    int v = blockIdx.x, t = blockIdx.y;  // t in 0..64
    int tid = threadIdx.x;
    int mt = tid >> 7, ks = (tid >> 6) & 1, lane = tid & 63;
    int b = mt * 16 + (lane & 15);
    int f = ks * 32 + ((lane >> 4) << 3);
    union { u16 u[8]; uint4 q; } pk;
    if (t < T) {
        const float* sp = &seq[((b * V + v) * T + t) * F + f];
        float4 x0 = *(const float4*)sp, x1 = *(const float4*)(sp + 4);
        pk.u[0] = f2bf(x0.x); pk.u[1] = f2bf(x0.y); pk.u[2] = f2bf(x0.z); pk.u[3] = f2bf(x0.w);
        pk.u[4] = f2bf(x1.x); pk.u[5] = f2bf(x1.y); pk.u[6] = f2bf(x1.z); pk.u[7] = f2bf(x1.w);
    } else {
        const float* sp = &seq[((b * V + v) * T + (T - 1)) * F + f];
        float4 x0 = *(const float4*)sp, x1 = *(const float4*)(sp + 4);
        float4 mx0 = *(const float4*)&maxval[b * F + f], mx1 = *(const float4*)&maxval[b * F + f + 4];
        float4 mn0 = *(const float4*)&minval[b * F + f], mn1 = *(const float4*)&minval[b * F + f + 4];
        pk.u[0] = f2bf(x0.x * (mx0.x - mn0.x) + mn0.x);
        pk.u[1] = f2bf(x0.y * (mx0.y - mn0.y) + mn0.y);
        pk.u[2] = f2bf(x0.z * (mx0.z - mn0.z) + mn0.z);
        pk.u[3] = f2bf(x0.w * (mx0.w - mn0.w) + mn0.w);
        pk.u[4] = f2bf(x1.x * (mx1.x - mn1.x) + mn1.x);
        pk.u[5] = f2bf(x1.y * (mx1.y - mn1.y) + mn1.y);
        pk.u[6] = f2bf(x1.z * (mx1.z - mn1.z) + mn1.z);
        pk.u[7] = f2bf(x1.w * (mx1.w - mn1.w) + mn1.w);
    }
    *(uint4*)&seqstg[(((size_t)(t * 16 + v)) * 4 + mt * 2 + ks) * 512 + lane * 8] = pk.q;
}

// ---------------------------------------------------------------------------
// Persistent recurrence: 65 steps, one launch, 256 blocks x 256 threads.
// block (v = bid&15, hk = bid>>4).
// Dependencies are GROUP-local:  phase A (v,hk) reads h[.,j,hk-slice] <- written
// by B(j,hk): same-hk family.  phase B (v,hk) reads whstg[v,*] <- written by
// A(v,hk'): same-v family.  So two 16-way barriers/step, no grid barrier.
// h and whstg cross blocks -> device-scope relaxed atomics (sc1, coherent at IF$).
// h double-buffered by step parity; whstg double-buffered by step parity (WAR).
__global__ __launch_bounds__(256) void k_recur(
    const u16* __restrict__ seqstg, const u16* __restrict__ Wstg,
    const float* __restrict__ w_all, const float* __restrict__ wmax_all,
    const float* __restrict__ b_ih, const float* __restrict__ b_hh,
    float* __restrict__ h0buf, float* __restrict__ h1buf,
    float* __restrict__ c, u16* __restrict__ enc, u16* __restrict__ whstg,
    unsigned* __restrict__ bar) {
    int bid = blockIdx.x;
    int v = bid & 15, hk = bid >> 4;
    int tid = threadIdx.x;
    __shared__ u16 Abuf[36 * 512];     // 36 KB
    __shared__ u16 Wbuf[2][8 * 512];   // 16 KB
    __shared__ float sw[32][16];       // 2 KB

    const u16* wks = Wstg + (size_t)((v * 16 + hk) * 18) * 4096;

    int lane = tid & 63, wvi = tid >> 6;
    int mtw = wvi & 1, hh = wvi >> 1;
    int col = hk * 32 + hh * 16 + (lane & 15);
    int q4 = (lane >> 4) << 2;
    float bi = b_ih[v * G4H + col] + b_hh[v * G4H + col];
    float bf_ = b_ih[v * G4H + H + col] + b_hh[v * G4H + H + col];
    float bg_ = b_ih[v * G4H + 2 * H + col] + b_hh[v * G4H + 2 * H + col];
    float bo = b_ih[v * G4H + 3 * H + col] + b_hh[v * G4H + 3 * H + col];

    unsigned* vcnt = bar + v * 16;          // v-group counter (64B padded)
    unsigned* hcnt = bar + (16 + hk) * 16;  // hk-group counter
    unsigned vtarget = 0, htarget = 0;

    // phase-A constants (threads 0..127)
    int amt = tid >> 6;          // 0..1
    int as6 = tid & 63;
    int ab = amt * 16 + (as6 & 15);
    int akhid = hk * 32 + (as6 >> 4) * 8;

    for (int t = 0; t <= T; ++t) {
        int p = t & 1;
        int tm = t < T ? t : (T - 1);
        const float* hin = (t & 1) ? h0buf : h1buf;
        float* hout = (t & 1) ? h1buf : h0buf;

        // stage seq chunks (ks 0,1 per mt) into Abuf; prefetch W ks=0
        {
            int ch = tid >> 6;
            int mt2 = ch >> 1, ks2 = ch & 1;
            uint4 sv = *(const uint4*)&seqstg[(((size_t)(t * 16 + v)) * 4 + mt2 * 2 + ks2) * 512 + lane * 8];
            *(uint4*)&Abuf[(mt2 * 18 + ks2) * 512 + lane * 8] = sv;
        }
        uint4 wa = *(const uint4*)&wks[tid * 8];
        uint4 wb = *(const uint4*)&wks[(tid + 256) * 8];
        for (int i = tid; i < 512; i += 256)
            sw[i >> 4][i & 15] = w_all[((size_t)tm * (B * V) + (i >> 4) * V + v) * V + (i & 15)];
        __syncthreads();

        // phase A: wh chunk (v, amt, ks=hk) from hin (coherent loads)
        if (tid < 128) {
            float inv = 1.0f / wmax_all[tm];
            float a0 = 0, a1 = 0, a2 = 0, a3 = 0, a4 = 0, a5 = 0, a6 = 0, a7 = 0;
#pragma unroll
            for (int j = 0; j < 16; ++j) {
                const ull* hq = (const ull*)&hin[(ab * V + j) * H + akhid];
                ull q0 = ld_agent(hq + 0), q1 = ld_agent(hq + 1);
                ull q2 = ld_agent(hq + 2), q3 = ld_agent(hq + 3);
                float wj = sw[ab][j];
                union { ull u; float f[2]; } u0, u1, u2, u3;
                u0.u = q0; u1.u = q1; u2.u = q2; u3.u = q3;
                a0 += wj * u0.f[0]; a1 += wj * u0.f[1];
                a2 += wj * u1.f[0]; a3 += wj * u1.f[1];
                a4 += wj * u2.f[0]; a5 += wj * u2.f[1];
                a6 += wj * u3.f[0]; a7 += wj * u3.f[1];
            }
            union { u16 u[8]; ull q[2]; } pk;
            pk.u[0] = f2bf(a0 * inv); pk.u[1] = f2bf(a1 * inv);
            pk.u[2] = f2bf(a2 * inv); pk.u[3] = f2bf(a3 * inv);
            pk.u[4] = f2bf(a4 * inv); pk.u[5] = f2bf(a5 * inv);
            pk.u[6] = f2bf(a6 * inv); pk.u[7] = f2bf(a7 * inv);
            ull* dst = (ull*)&whstg[p * WHP + (((v * 2 + amt) * 16 + hk) * 64 + as6) * 8];
            st_agent(dst + 0, pk.q[0]);
            st_agent(dst + 1, pk.q[1]);
        }

        // v-group barrier: whstg[p][v,*] complete
        vtarget += 16;
        bar_sync(vcnt, vtarget);

        // stage wh chunks (ks 2..17 per mt) into Abuf (coherent loads)
#pragma unroll
        for (int i = 0; i < 8; ++i) {
            int task = tid + i * 256;
            int ch = task >> 6, ln = task & 63;
            int mt2 = ch >> 4, ksw = ch & 15;
            const ull* src = (const ull*)&whstg[p * WHP + (((v * 2 + mt2) * 16 + ksw) * 64 + ln) * 8];
            ull a0 = ld_agent(src + 0), a1 = ld_agent(src + 1);
            ull* d = (ull*)&Abuf[(mt2 * 18 + 2 + ksw) * 512 + ln * 8];
            d[0] = a0; d[1] = a1;
        }
        *(uint4*)&Wbuf[0][tid * 8] = wa;
        *(uint4*)&Wbuf[0][(tid + 256) * 8] = wb;
        wa = *(const uint4*)&wks[4096 + tid * 8];
        wb = *(const uint4*)&wks[4096 + (tid + 256) * 8];
        __syncthreads();

        f32x4 acc[4];
#pragma unroll
        for (int g = 0; g < 4; ++g) { acc[g][0] = 0.f; acc[g][1] = 0.f; acc[g][2] = 0.f; acc[g][3] = 0.f; }

        for (int ks = 0; ks < 18; ++ks) {
            int cur = ks & 1;
            bf16x8 af = *(const bf16x8*)&Abuf[(mtw * 18 + ks) * 512 + lane * 8];
#pragma unroll
            for (int g = 0; g < 4; ++g) {
                bf16x8 bfr = *(const bf16x8*)&Wbuf[cur][((g << 1) + hh) * 512 + lane * 8];
                acc[g] = mfma16(af, bfr, acc[g]);
            }
            if (ks < 17) {
                *(uint4*)&Wbuf[cur ^ 1][tid * 8] = wa;
                *(uint4*)&Wbuf[cur ^ 1][(tid + 256) * 8] = wb;
                if (ks < 16) {
                    wa = *(const uint4*)&wks[(size_t)(ks + 2) * 4096 + tid * 8];
                    wb = *(const uint4*)&wks[(size_t)(ks + 2) * 4096 + (tid + 256) * 8];
                }
                __syncthreads();
            }
        }

        // epilogue: c (block-private, cached), h (coherent), enc (cached)
#pragma unroll
        for (int r = 0; r < 4; ++r) {
            int b = mtw * 16 + q4 + r;
            float gi = acc[0][r] + bi;
            float gf = acc[1][r] + bf_;
            float gg = acc[2][r] + bg_;
            float go = acc[3][r] + bo;
            int idx = (b * V + v) * H + col;
            float cn = sigmoidf_(gf) * c[idx] + sigmoidf_(gi) * tanhf(gg);
            float hn = sigmoidf_(go) * tanhf(cn);
            c[idx] = cn;
            st_agent_f(&hout[idx], hn);
            if (t < T) enc[((size_t)(b * V + v) * T + t) * H + col] = f2bf(hn);
        }

        // hk-group barrier: h[.,.,hk-slice] complete for next step's phase A
        if (t < T) {
            htarget += 16;
            bar_sync(hcnt, htarget);
        }
    }
}

// ---------------------------------------------------------------------------
// soft attention over bf16 enc.  block=(b,v)
__global__ __launch_bounds__(256) void k_attn(
    const u16* __restrict__ enc, const float* __restrict__ h,
    const float* __restrict__ mask, float* __restrict__ ctx) {
    int bid = blockIdx.x;
    int b = bid >> 4, v = bid & 15;
    int tid = threadIdx.x;
    int wave = tid >> 6, lane = tid & 63;
    __shared__ float hs[H];
    __shared__ float sc[T];
    __shared__ float al[T];
    const u16* encbase = enc + (size_t)((b * V + v) * T) * H;
    const float* hb = h + (b * V + v) * H;
    for (int i = tid; i < H; i += 256) hs[i] = hb[i];
    __syncthreads();
    for (int tt = wave; tt < T; tt += 4) {
        const u16* e = encbase + tt * H;
        float p = 0.0f;
#pragma unroll
        for (int ii = 0; ii < 8; ++ii) p += bf2f(e[ii * 64 + lane]) * hs[ii * 64 + lane];
        for (int off = 32; off; off >>= 1) p += __shfl_down(p, off, 64);
        if (lane == 0) sc[tt] = p;
    }
    __syncthreads();
    if (tid < 64) {
        float m_t = mask[(b * V + v) * T + tid];
        float s = sc[tid] * m_t;
        float mx = s;
        for (int off = 32; off; off >>= 1) mx = fmaxf(mx, __shfl_xor(mx, off, 64));
        float e = __expf(s - mx);
        float sum = e;
        for (int off = 32; off; off >>= 1) sum += __shfl_xor(sum, off, 64);
        al[tid] = e / sum;
    }
    __syncthreads();
    for (int hh = tid; hh < H; hh += 256) {
        float a = 0.0f;
        for (int tt = 0; tt < T; ++tt) a += al[tt] * bf2f(encbase[tt * H + hh]);
        ctx[(b * V + v) * H + hh] = a;
    }
}

// ---------------------------------------------------------------------------
// per-vessel soft linear (torch stack/view reinterleave).  grid (16,16), 32-col tiles.
__global__ __launch_bounds__(256) void k_soft(
    const float* __restrict__ ctx, const float* __restrict__ hdec,
    const float* __restrict__ soft_W, const float* __restrict__ soft_b,
    float* __restrict__ hsoft) {
    int v = blockIdx.x;
    int h0 = blockIdx.y * 32;
    int tid = threadIdx.x;
    int cg = tid & 31, rg = tid >> 5;
    __shared__ float sA[32][36];
    __shared__ float sW2[32][36];
    float* sAf = &sA[0][0];
    float* sWf = &sW2[0][0];
    float acc[4] = {0.f, 0.f, 0.f, 0.f};
    int arow = tid >> 3, akq = tid & 7;
    float4 areg, wreg;

    {
        int k = akq * 4;
        const float* src = (arow < 16) ? ctx : hdec;
        int bsrc = 2 * (arow & 15) + (k >= H ? 1 : 0);
        areg = *(const float4*)&src[(bsrc * V + v) * H + (k & (H - 1))];
        wreg = *(const float4*)&soft_W[(v * H + h0 + arow) * (2 * H) + k];
    }
    for (int kc = 0; kc < 2 * H; kc += 32) {
        __syncthreads();
        *(float4*)&sAf[arow * 36 + akq * 4] = areg;
        *(float4*)&sWf[arow * 36 + akq * 4] = wreg;
        __syncthreads();
        if (kc + 32 < 2 * H) {
            int k = kc + 32 + akq * 4;
            const float* src = (arow < 16) ? ctx : hdec;
            int bsrc = 2 * (arow & 15) + (k >= H ? 1 : 0);
            areg = *(const float4*)&src[(bsrc * V + v) * H + (k & (H - 1))];
            wreg = *(const float4*)&soft_W[(v * H + h0 + arow) * (2 * H) + kc + 32 + akq * 4];
        }
#pragma unroll
        for (int k4 = 0; k4 < 8; ++k4) {
            float4 wv = *(const float4*)&sWf[cg * 36 + k4 * 4];
            float4 a0 = *(const float4*)&sAf[(rg * 4 + 0) * 36 + k4 * 4];
            float4 a1 = *(const float4*)&sAf[(rg * 4 + 1) * 36 + k4 * 4];
            float4 a2 = *(const float4*)&sAf[(rg * 4 + 2) * 36 + k4 * 4];
            float4 a3 = *(const float4*)&sAf[(rg * 4 + 3) * 36 + k4 * 4];
            acc[0] += a0.x * wv.x + a0.y * wv.y + a0.z * wv.z + a0.w * wv.w;
            acc[1] += a1.x * wv.x + a1.y * wv.y + a1.z * wv.z + a1.w * wv.w;
            acc[2] += a2.x * wv.x + a2.y * wv.y + a2.z * wv.z + a2.w * wv.w;
            acc[3] += a3.x * wv.x + a3.y * wv.y + a3.z * wv.z + a3.w * wv.w;
        }
    }
    float bb = soft_b[v * H + h0 + cg];
#pragma unroll
    for (int r = 0; r < 4; ++r) {
        int row = rg * 4 + r;
        hsoft[(row * V + v) * H + h0 + cg] = tanhf(acc[r] + bb);
    }
}

// ---------------------------------------------------------------------------
__global__ __launch_bounds__(64) void k_out(
    const float* __restrict__ hsoft, const float* __restrict__ outW,
    const float* __restrict__ outb, float* __restrict__ out) {
    int bid = blockIdx.x;
    int b = bid >> 4, v = bid & 15;
    int lane = threadIdx.x;
    const float* hb = hsoft + (b * V + v) * H;
    float p[4] = {0.0f, 0.0f, 0.0f, 0.0f};
#pragma unroll
    for (int ii = 0; ii < 8; ++ii) {
        float hv = hb[ii * 64 + lane];
#pragma unroll
        for (int o = 0; o < 4; ++o) p[o] += hv * outW[o * H + ii * 64 + lane];
    }
#pragma unroll
    for (int o = 0; o < 4; ++o) {
        float s = p[o];
        for (int off = 32; off; off >>= 1) s += __shfl_down(s, off, 64);
        if (lane == 0) {
            float val = s + outb[o];
            out[(b * V + v) * 4 + o] = val > 0.0f ? val : 0.0f;
        }
    }
}

// ---------------------------------------------------------------------------
extern "C" void kernel_launch(void* const* d_in, const int* in_sizes, int n_in,
                              void* d_out, int out_size, void* d_ws, size_t ws_size,
                              hipStream_t stream) {
    const float* seq = (const float*)d_in[0];
    const float* dist = (const float*)d_in[1];
    const int* rb = (const int*)d_in[2];
    const int* cog = (const int*)d_in[3];
    const float* mask = (const float*)d_in[4];
    const float* maxval = (const float*)d_in[5];
    const float* minval = (const float*)d_in[6];
    const float* W_ih = (const float*)d_in[7];
    const float* W_hh = (const float*)d_in[8];
    const float* b_ih = (const float*)d_in[9];
    const float* b_hh = (const float*)d_in[10];
    const float* domain = (const float*)d_in[11];
    const float* soft_W = (const float*)d_in[12];
    const float* soft_b = (const float*)d_in[13];
    const float* out_W = (const float*)d_in[14];
    const float* out_b = (const float*)d_in[15];

    float* ws = (float*)d_ws;
    float* h0buf = ws + OFF_H0;
    float* h1buf = ws + OFF_H1;
    float* c = ws + OFF_C;
    unsigned* bar = (unsigned*)(ws + OFF_CNT);
    float* w_all = ws + OFF_WALL;
    float* ctx = ws + OFF_CTX;      // alias (w_all dead after k_recur)
    float* hsoft = ws + OFF_HSOFT;  // alias
    float* wmax_all = ws + OFF_WMAX;
    u16* whstg = (u16*)(ws + OFF_WHSTG);
    u16* seqstg = (u16*)(ws + OFF_SEQSTG);
    u16* Wstg = (u16*)(ws + OFF_WSTG);
    u16* enc = (u16*)(ws + OFF_ENC);

    // zero h0,h1,c + barrier counters (contiguous [0, 786944))
    k_zero<<<3074, 256, 0, stream>>>(ws, 786944);
    k_hw_all<<<T, 256, 0, stream>>>(dist, rb, cog, mask, domain, w_all, wmax_all);
    k_wconv<<<dim3(16, 16, 18), 256, 0, stream>>>(W_ih, W_hh, Wstg);
    k_seqstg<<<dim3(16, T + 1), 256, 0, stream>>>(seq, maxval, minval, seqstg);

    // whole recurrence (64 encoder steps + 1 decoder step) in one launch
    k_recur<<<256, 256, 0, stream>>>(seqstg, Wstg, w_all, wmax_all, b_ih, b_hh,
                                     h0buf, h1buf, c, enc, whstg, bar);

    // final h is in h0buf (t=64 writes buf[0])
    k_attn<<<B * V, 256, 0, stream>>>(enc, h0buf, mask, ctx);
    k_soft<<<dim3(16, 16), 256, 0, stream>>>(ctx, h0buf, soft_W, soft_b, hsoft);
    k_out<<<B * V, 64, 0, stream>>>(hsoft, out_W, out_b, (float*)d_out);
}

// Round 6
// 1115.827 us; speedup vs baseline: 2.9629x; 1.1588x over previous
//
#include <hip/hip_runtime.h>
#include <math.h>

#define B 32
#define V 16
#define T 64
#define F 64
#define H 512
#define NB 36
#define G4H 2048

typedef unsigned short u16;
typedef unsigned long long ull;
typedef __attribute__((ext_vector_type(8))) short bf16x8;
typedef __attribute__((ext_vector_type(4))) float f32x4;

// workspace offsets (float units)
#define OFF_H0     0           // 262144
#define OFF_H1     262144      // 262144
#define OFF_C      524288      // 262144
#define OFF_CNT    786432      // 512 (32 barrier counters, 64B-padded)
#define OFF_WALL   786944      // 524288 fp32 w_all; ctx/hsoft alias (dead after k_recur)
#define OFF_CTX    786944      // 262144 (alias)
#define OFF_HSOFT  1049088     // 262144 (alias)
#define OFF_WMAX   1311232     // 64
#define OFF_WHSTG  1311296     // 262144 fl = 2 parities x 262144 u16 (wh, A-frag bf16)
#define OFF_SEQSTG 1573440     // 1064960 fl = 2129920 u16 (seq all t + denorm t=64, A-frag)
#define OFF_WSTG   2638400     // 9437184 fl (weights, B-frag bf16)
#define OFF_ENC    12075584    // 8388608 fl = 16777216 u16 (enc bf16)
// total 20,464,192 fl = 81.9 MB

#define WHP 262144   // u16 per whstg parity

__device__ __forceinline__ float sigmoidf_(float x) { return 1.0f / (1.0f + __expf(-x)); }

__device__ __forceinline__ u16 f2bf(float f) {  // RNE fp32->bf16
    union { float f; unsigned u; } x; x.f = f;
    unsigned r = x.u + 0x7FFF + ((x.u >> 16) & 1);
    return (u16)(r >> 16);
}
__device__ __forceinline__ float bf2f(u16 u) {
    union { unsigned i; float f; } x; x.i = ((unsigned)u) << 16;
    return x.f;
}
__device__ __forceinline__ f32x4 mfma16(bf16x8 a, bf16x8 b, f32x4 c) {
    return __builtin_amdgcn_mfma_f32_16x16x32_bf16(a, b, c, 0, 0, 0);
}

// device-scope coherent accesses (serviced at the coherence point; no fences)
__device__ __forceinline__ ull ld_agent(const ull* p) {
    return __hip_atomic_load((ull*)p, __ATOMIC_RELAXED, __HIP_MEMORY_SCOPE_AGENT);
}
__device__ __forceinline__ void st_agent(ull* p, ull x) {
    __hip_atomic_store(p, x, __ATOMIC_RELAXED, __HIP_MEMORY_SCOPE_AGENT);
}
__device__ __forceinline__ void st_agent_f(float* p, float x) {
    __hip_atomic_store(p, x, __ATOMIC_RELAXED, __HIP_MEMORY_SCOPE_AGENT);
}

// 16-way group barrier: relaxed monotone counter; visibility via sc1 data
// accesses; ordering via s_waitcnt drain at __syncthreads/arrival.
__device__ __forceinline__ void bar_sync(unsigned* cnt, unsigned target) {
    __syncthreads();
    if (threadIdx.x == 0) {
        __builtin_amdgcn_s_waitcnt(0);
        __hip_atomic_fetch_add(cnt, 1u, __ATOMIC_RELAXED, __HIP_MEMORY_SCOPE_AGENT);
        while (__hip_atomic_load(cnt, __ATOMIC_RELAXED, __HIP_MEMORY_SCOPE_AGENT) < target)
            __builtin_amdgcn_s_sleep(1);
    }
    __syncthreads();
}

// ---------------------------------------------------------------------------
__global__ void k_zero(float* __restrict__ p, int n) {
    int i = blockIdx.x * blockDim.x + threadIdx.x;
    if (i < n) p[i] = 0.0f;
}

// ---------------------------------------------------------------------------
// hardwired weights for all t: w_all[t][b][i][j] fp32 + wmax_all[t]
__global__ __launch_bounds__(256) void k_hw_all(
    const float* __restrict__ dist, const int* __restrict__ rb,
    const int* __restrict__ cog, const float* __restrict__ mask,
    const float* __restrict__ domain, float* __restrict__ w_all,
    float* __restrict__ wmax_all) {
    int t = blockIdx.x;
    __shared__ float red[256];
    int tid = threadIdx.x;
    float lmax = 0.0f;
    for (int idx = tid; idx < B * V * V; idx += 256) {
        int b = idx >> 8;
        int rem = idx & 255;
        int i = rem >> 4, j = rem & 15;
        int base = ((b * V + i) * T + t) * V + j;
        float val = domain[cog[base] * NB + rb[base]] - dist[base];
        val = val > 0.0f ? val : 0.0f;
        val *= mask[(b * V + i) * T + t] * mask[(b * V + j) * T + t];
        w_all[t * (B * V * V) + idx] = val;
        lmax = fmaxf(lmax, val);
    }
    red[tid] = lmax;
    __syncthreads();
    for (int s = 128; s > 0; s >>= 1) {
        if (tid < s) red[tid] = fmaxf(red[tid], red[tid + s]);
        __syncthreads();
    }
    if (tid == 0) wmax_all[t] = red[0];
}

// ---------------------------------------------------------------------------
// One-time: W_ih||W_hh (fp32, K-minor) -> bf16 B-fragment layout
// Wstg[v][hk16][ks18][nt8][lane64][8]; nt=g*2+hh; col=g*512+hk*32+hh*16+(lane&15)
__global__ __launch_bounds__(256) void k_wconv(
    const float* __restrict__ W_ih, const float* __restrict__ W_hh,
    u16* __restrict__ Wstg) {
    int v = blockIdx.x, hk = blockIdx.y, ks = blockIdx.z;
    int tid = threadIdx.x;
#pragma unroll
    for (int s = 0; s < 2; ++s) {
        int slot = tid + s * 256;
        int nt = slot >> 6, lane = slot & 63;
        int g = nt >> 1, hh = nt & 1;
        int col = g * H + hk * 32 + hh * 16 + (lane & 15);
        int k = ks * 32 + ((lane >> 4) << 3);
        const float* src = (k < F) ? &W_ih[(v * G4H + col) * F + k]
                                   : &W_hh[(v * G4H + col) * H + (k - F)];
        float4 x0 = *(const float4*)src;
        float4 x1 = *(const float4*)(src + 4);
        union { u16 u[8]; uint4 q; } pk;
        pk.u[0] = f2bf(x0.x); pk.u[1] = f2bf(x0.y); pk.u[2] = f2bf(x0.z); pk.u[3] = f2bf(x0.w);
        pk.u[4] = f2bf(x1.x); pk.u[5] = f2bf(x1.y); pk.u[6] = f2bf(x1.z); pk.u[7] = f2bf(x1.w);
        *(uint4*)&Wstg[(size_t)((((v * 16 + hk) * 18 + ks) * 8 + nt) * 64 + lane) * 8] = pk.q;
    }
}

// ---------------------------------------------------------------------------
// One-time: pack seq for all t (t=64 = denormalized last input) into A-frag bf16:
// seqstg[t][v][mt2][ks2][lane64][8]
__global__ __launch_bounds__(256) void k_seqstg(
    const float* __restrict__ seq, const float* __restrict__ maxval,
    const float* __restrict__ minval, u16* __restrict__ seqstg) {
    int v = blockIdx.x, t = blockIdx.y;  // t in 0..64
    int tid = threadIdx.x;
    int mt = tid >> 7, ks = (tid >> 6) & 1, lane = tid & 63;
    int b = mt * 16 + (lane & 15);
    int f = ks * 32 + ((lane >> 4) << 3);
    union { u16 u[8]; uint4 q; } pk;
    if (t < T) {
        const float* sp = &seq[((b * V + v) * T + t) * F + f];
        float4 x0 = *(const float4*)sp, x1 = *(const float4*)(sp + 4);
        pk.u[0] = f2bf(x0.x); pk.u[1] = f2bf(x0.y); pk.u[2] = f2bf(x0.z); pk.u[3] = f2bf(x0.w);
        pk.u[4] = f2bf(x1.x); pk.u[5] = f2bf(x1.y); pk.u[6] = f2bf(x1.z); pk.u[7] = f2bf(x1.w);
    } else {
        const float* sp = &seq[((b * V + v) * T + (T - 1)) * F + f];
        float4 x0 = *(const float4*)sp, x1 = *(const float4*)(sp + 4);
        float4 mx0 = *(const float4*)&maxval[b * F + f], mx1 = *(const float4*)&maxval[b * F + f + 4];
        float4 mn0 = *(const float4*)&minval[b * F + f], mn1 = *(const float4*)&minval[b * F + f + 4];
        pk.u[0] = f2bf(x0.x * (mx0.x - mn0.x) + mn0.x);
        pk.u[1] = f2bf(x0.y * (mx0.y - mn0.y) + mn0.y);
        pk.u[2] = f2bf(x0.z * (mx0.z - mn0.z) + mn0.z);
        pk.u[3] = f2bf(x0.w * (mx0.w - mn0.w) + mn0.w);
        pk.u[4] = f2bf(x1.x * (mx1.x - mn1.x) + mn1.x);
        pk.u[5] = f2bf(x1.y * (mx1.y - mn1.y) + mn1.y);
        pk.u[6] = f2bf(x1.z * (mx1.z - mn1.z) + mn1.z);
        pk.u[7] = f2bf(x1.w * (mx1.w - mn1.w) + mn1.w);
    }
    *(uint4*)&seqstg[(((size_t)(t * 16 + v)) * 4 + mt * 2 + ks) * 512 + lane * 8] = pk.q;
}

// ---------------------------------------------------------------------------
// Persistent recurrence: 65 steps, one launch, 256 blocks x 256 threads.
// block (v = bid&15, hk = bid>>4).  Two 16-way group barriers per step
// (validated in R5).  This round: W streamed per-wave straight from global
// into a depth-4 register pipeline (Wstg is already fragment-ordered) -- no
// LDS for W, no syncthreads in the K-loop.  W prefetch for ks=0..3 is issued
// BEFORE phase A so its latency hides behind A + v-barrier.
__global__ __launch_bounds__(256) void k_recur(
    const u16* __restrict__ seqstg, const u16* __restrict__ Wstg,
    const float* __restrict__ w_all, const float* __restrict__ wmax_all,
    const float* __restrict__ b_ih, const float* __restrict__ b_hh,
    float* __restrict__ h0buf, float* __restrict__ h1buf,
    float* __restrict__ c, u16* __restrict__ enc, u16* __restrict__ whstg,
    unsigned* __restrict__ bar) {
    int bid = blockIdx.x;
    int v = bid & 15, hk = bid >> 4;
    int tid = threadIdx.x;
    __shared__ u16 Abuf[36 * 512];   // 36 KB: [mt*18+ks][lane][8]
    __shared__ float sw[32][16];     // 2 KB

    const u16* wks = Wstg + (size_t)((v * 16 + hk) * 18) * 4096;

    int lane = tid & 63, wvi = tid >> 6;
    int mtw = wvi & 1, hh = wvi >> 1;
    int col = hk * 32 + hh * 16 + (lane & 15);
    int q4 = (lane >> 4) << 2;
    float bi = b_ih[v * G4H + col] + b_hh[v * G4H + col];
    float bf_ = b_ih[v * G4H + H + col] + b_hh[v * G4H + H + col];
    float bg_ = b_ih[v * G4H + 2 * H + col] + b_hh[v * G4H + 2 * H + col];
    float bo = b_ih[v * G4H + 3 * H + col] + b_hh[v * G4H + 3 * H + col];

    unsigned* vcnt = bar + v * 16;          // v-group counter (64B padded)
    unsigned* hcnt = bar + (16 + hk) * 16;  // hk-group counter
    unsigned vtarget = 0, htarget = 0;

    // phase-A constants: all 256 threads; thread = (b, quad, half)
    int ab = tid >> 3;               // 0..31 batch
    int asub = tid & 7;
    int aq = asub >> 1, ah = asub & 1;
    int akhid = hk * 32 + aq * 8 + ah * 4;
    int alane = aq * 16 + (ab & 15);
    int amt = ab >> 4;

    for (int t = 0; t <= T; ++t) {
        int p = t & 1;
        int tm = t < T ? t : (T - 1);
        const float* hin = (t & 1) ? h0buf : h1buf;
        float* hout = (t & 1) ? h1buf : h0buf;

        // ---- W register prefetch, chunks ks=0..3 (latency hidden by A+vbar)
        bf16x8 wf[4][4];
#pragma unroll
        for (int d = 0; d < 4; ++d)
#pragma unroll
            for (int g = 0; g < 4; ++g)
                wf[d][g] = *(const bf16x8*)&wks[(d * 8 + (g * 2 + hh)) * 512 + lane * 8];

        // ---- stage seq chunks (ks 0,1 per mt) into Abuf (cached loads)
        {
            int ch = tid >> 6;
            int mt2 = ch >> 1, ks2 = ch & 1;
            uint4 sv = *(const uint4*)&seqstg[(((size_t)(t * 16 + v)) * 4 + mt2 * 2 + ks2) * 512 + lane * 8];
            *(uint4*)&Abuf[(mt2 * 18 + ks2) * 512 + lane * 8] = sv;
        }
        // ---- hardwired w rows for this v
        for (int i = tid; i < 512; i += 256)
            sw[i >> 4][i & 15] = w_all[((size_t)tm * (B * V) + (i >> 4) * V + v) * V + (i & 15)];
        __syncthreads();

        // ---- phase A: wh(v, b=ab, hidden akhid..+4) from hin (sc1 loads)
        {
            float inv = 1.0f / wmax_all[tm];
            float a0 = 0.f, a1 = 0.f, a2 = 0.f, a3 = 0.f;
#pragma unroll
            for (int j = 0; j < 16; ++j) {
                const ull* hq = (const ull*)&hin[(ab * V + j) * H + akhid];
                ull q0 = ld_agent(hq), q1 = ld_agent(hq + 1);
                union { ull u; float f[2]; } u0, u1;
                u0.u = q0; u1.u = q1;
                float wj = sw[ab][j];
                a0 += wj * u0.f[0]; a1 += wj * u0.f[1];
                a2 += wj * u1.f[0]; a3 += wj * u1.f[1];
            }
            union { u16 u[4]; ull q; } pk;
            pk.u[0] = f2bf(a0 * inv); pk.u[1] = f2bf(a1 * inv);
            pk.u[2] = f2bf(a2 * inv); pk.u[3] = f2bf(a3 * inv);
            st_agent((ull*)&whstg[p * WHP + (((v * 2 + amt) * 16 + hk) * 64 + alane) * 8 + ah * 4],
                     pk.q);
        }

        // ---- v-group barrier: whstg[p][v,*] complete
        vtarget += 16;
        bar_sync(vcnt, vtarget);

        // ---- stage wh chunks (ks 2..17 per mt) into Abuf (sc1 loads)
#pragma unroll
        for (int i = 0; i < 8; ++i) {
            int task = tid + i * 256;
            int ch = task >> 6, ln = task & 63;
            int mt2 = ch >> 4, ksw = ch & 15;
            const ull* src = (const ull*)&whstg[p * WHP + (((v * 2 + mt2) * 16 + ksw) * 64 + ln) * 8];
            ull a0 = ld_agent(src + 0), a1 = ld_agent(src + 1);
            ull* d = (ull*)&Abuf[(mt2 * 18 + 2 + ksw) * 512 + ln * 8];
            d[0] = a0; d[1] = a1;
        }
        __syncthreads();

        // ---- K-loop: 18 chunks, no syncs; depth-4 register W pipeline
        f32x4 acc[4];
#pragma unroll
        for (int g = 0; g < 4; ++g) { acc[g][0] = 0.f; acc[g][1] = 0.f; acc[g][2] = 0.f; acc[g][3] = 0.f; }

#pragma unroll
        for (int ks = 0; ks < 18; ++ks) {
            bf16x8 af = *(const bf16x8*)&Abuf[(mtw * 18 + ks) * 512 + lane * 8];
#pragma unroll
            for (int g = 0; g < 4; ++g)
                acc[g] = mfma16(af, wf[ks & 3][g], acc[g]);
            if (ks + 4 < 18) {
#pragma unroll
                for (int g = 0; g < 4; ++g)
                    wf[ks & 3][g] = *(const bf16x8*)&wks[((ks + 4) * 8 + (g * 2 + hh)) * 512 + lane * 8];
            }
        }

        // ---- epilogue: c (block-private, cached), h (sc1), enc (cached)
#pragma unroll
        for (int r = 0; r < 4; ++r) {
            int b = mtw * 16 + q4 + r;
            float gi = acc[0][r] + bi;
            float gf = acc[1][r] + bf_;
            float gg = acc[2][r] + bg_;
            float go = acc[3][r] + bo;
            int idx = (b * V + v) * H + col;
            float cn = sigmoidf_(gf) * c[idx] + sigmoidf_(gi) * tanhf(gg);
            float hn = sigmoidf_(go) * tanhf(cn);
            c[idx] = cn;
            st_agent_f(&hout[idx], hn);
            if (t < T) enc[((size_t)(b * V + v) * T + t) * H + col] = f2bf(hn);
        }

        // ---- hk-group barrier: h[.,.,hk-slice] ready for next step's phase A
        if (t < T) {
            htarget += 16;
            bar_sync(hcnt, htarget);
        }
    }
}

// ---------------------------------------------------------------------------
// soft attention over bf16 enc.  block=(b,v)
__global__ __launch_bounds__(256) void k_attn(
    const u16* __restrict__ enc, const float* __restrict__ h,
    const float* __restrict__ mask, float* __restrict__ ctx) {
    int bid = blockIdx.x;
    int b = bid >> 4, v = bid & 15;
    int tid = threadIdx.x;
    int wave = tid >> 6, lane = tid & 63;
    __shared__ float hs[H];
    __shared__ float sc[T];
    __shared__ float al[T];
    const u16* encbase = enc + (size_t)((b * V + v) * T) * H;
    const float* hb = h + (b * V + v) * H;
    for (int i = tid; i < H; i += 256) hs[i] = hb[i];
    __syncthreads();
    for (int tt = wave; tt < T; tt += 4) {
        const u16* e = encbase + tt * H;
        float p = 0.0f;
#pragma unroll
        for (int ii = 0; ii < 8; ++ii) p += bf2f(e[ii * 64 + lane]) * hs[ii * 64 + lane];
        for (int off = 32; off; off >>= 1) p += __shfl_down(p, off, 64);
        if (lane == 0) sc[tt] = p;
    }
    __syncthreads();
    if (tid < 64) {
        float m_t = mask[(b * V + v) * T + tid];
        float s = sc[tid] * m_t;
        float mx = s;
        for (int off = 32; off; off >>= 1) mx = fmaxf(mx, __shfl_xor(mx, off, 64));
        float e = __expf(s - mx);
        float sum = e;
        for (int off = 32; off; off >>= 1) sum += __shfl_xor(sum, off, 64);
        al[tid] = e / sum;
    }
    __syncthreads();
    for (int hh = tid; hh < H; hh += 256) {
        float a = 0.0f;
        for (int tt = 0; tt < T; ++tt) a += al[tt] * bf2f(encbase[tt * H + hh]);
        ctx[(b * V + v) * H + hh] = a;
    }
}

// ---------------------------------------------------------------------------
// per-vessel soft linear (torch stack/view reinterleave).  grid (16,16), 32-col tiles.
__global__ __launch_bounds__(256) void k_soft(
    const float* __restrict__ ctx, const float* __restrict__ hdec,
    const float* __restrict__ soft_W, const float* __restrict__ soft_b,
    float* __restrict__ hsoft) {
    int v = blockIdx.x;
    int h0 = blockIdx.y * 32;
    int tid = threadIdx.x;
    int cg = tid & 31, rg = tid >> 5;
    __shared__ float sA[32][36];
    __shared__ float sW2[32][36];
    float* sAf = &sA[0][0];
    float* sWf = &sW2[0][0];
    float acc[4] = {0.f, 0.f, 0.f, 0.f};
    int arow = tid >> 3, akq = tid & 7;
    float4 areg, wreg;

    {
        int k = akq * 4;
        const float* src = (arow < 16) ? ctx : hdec;
        int bsrc = 2 * (arow & 15) + (k >= H ? 1 : 0);
        areg = *(const float4*)&src[(bsrc * V + v) * H + (k & (H - 1))];
        wreg = *(const float4*)&soft_W[(v * H + h0 + arow) * (2 * H) + k];
    }
    for (int kc = 0; kc < 2 * H; kc += 32) {
        __syncthreads();
        *(float4*)&sAf[arow * 36 + akq * 4] = areg;
        *(float4*)&sWf[arow * 36 + akq * 4] = wreg;
        __syncthreads();
        if (kc + 32 < 2 * H) {
            int k = kc + 32 + akq * 4;
            const float* src = (arow < 16) ? ctx : hdec;
            int bsrc = 2 * (arow & 15) + (k >= H ? 1 : 0);
            areg = *(const float4*)&src[(bsrc * V + v) * H + (k & (H - 1))];
            wreg = *(const float4*)&soft_W[(v * H + h0 + arow) * (2 * H) + kc + 32 + akq * 4];
        }
#pragma unroll
        for (int k4 = 0; k4 < 8; ++k4) {
            float4 wv = *(const float4*)&sWf[cg * 36 + k4 * 4];
            float4 a0 = *(const float4*)&sAf[(rg * 4 + 0) * 36 + k4 * 4];
            float4 a1 = *(const float4*)&sAf[(rg * 4 + 1) * 36 + k4 * 4];
            float4 a2 = *(const float4*)&sAf[(rg * 4 + 2) * 36 + k4 * 4];
            float4 a3 = *(const float4*)&sAf[(rg * 4 + 3) * 36 + k4 * 4];
            acc[0] += a0.x * wv.x + a0.y * wv.y + a0.z * wv.z + a0.w * wv.w;
            acc[1] += a1.x * wv.x + a1.y * wv.y + a1.z * wv.z + a1.w * wv.w;
            acc[2] += a2.x * wv.x + a2.y * wv.y + a2.z * wv.z + a2.w * wv.w;
            acc[3] += a3.x * wv.x + a3.y * wv.y + a3.z * wv.z + a3.w * wv.w;
        }
    }
    float bb = soft_b[v * H + h0 + cg];
#pragma unroll
    for (int r = 0; r < 4; ++r) {
        int row = rg * 4 + r;
        hsoft[(row * V + v) * H + h0 + cg] = tanhf(acc[r] + bb);
    }
}

// ---------------------------------------------------------------------------
__global__ __launch_bounds__(64) void k_out(
    const float* __restrict__ hsoft, const float* __restrict__ outW,
    const float* __restrict__ outb, float* __restrict__ out) {
    int bid = blockIdx.x;
    int b = bid >> 4, v = bid & 15;
    int lane = threadIdx.x;
    const float* hb = hsoft + (b * V + v) * H;
    float p[4] = {0.0f, 0.0f, 0.0f, 0.0f};
#pragma unroll
    for (int ii = 0; ii < 8; ++ii) {
        float hv = hb[ii * 64 + lane];
#pragma unroll
        for (int o = 0; o < 4; ++o) p[o] += hv * outW[o * H + ii * 64 + lane];
    }
#pragma unroll
    for (int o = 0; o < 4; ++o) {
        float s = p[o];
        for (int off = 32; off; off >>= 1) s += __shfl_down(s, off, 64);
        if (lane == 0) {
            float val = s + outb[o];
            out[(b * V + v) * 4 + o] = val > 0.0f ? val : 0.0f;
        }
    }
}

// ---------------------------------------------------------------------------
extern "C" void kernel_launch(void* const* d_in, const int* in_sizes, int n_in,
                              void* d_out, int out_size, void* d_ws, size_t ws_size,
                              hipStream_t stream) {
    const float* seq = (const float*)d_in[0];
    const float* dist = (const float*)d_in[1];
    const int* rb = (const int*)d_in[2];
    const int* cog = (const int*)d_in[3];
    const float* mask = (const float*)d_in[4];
    const float* maxval = (const float*)d_in[5];
    const float* minval = (const float*)d_in[6];
    const float* W_ih = (const float*)d_in[7];
    const float* W_hh = (const float*)d_in[8];
    const float* b_ih = (const float*)d_in[9];
    const float* b_hh = (const float*)d_in[10];
    const float* domain = (const float*)d_in[11];
    const float* soft_W = (const float*)d_in[12];
    const float* soft_b = (const float*)d_in[13];
    const float* out_W = (const float*)d_in[14];
    const float* out_b = (const float*)d_in[15];

    float* ws = (float*)d_ws;
    float* h0buf = ws + OFF_H0;
    float* h1buf = ws + OFF_H1;
    float* c = ws + OFF_C;
    unsigned* bar = (unsigned*)(ws + OFF_CNT);
    float* w_all = ws + OFF_WALL;
    float* ctx = ws + OFF_CTX;      // alias (w_all dead after k_recur)
    float* hsoft = ws + OFF_HSOFT;  // alias
    float* wmax_all = ws + OFF_WMAX;
    u16* whstg = (u16*)(ws + OFF_WHSTG);
    u16* seqstg = (u16*)(ws + OFF_SEQSTG);
    u16* Wstg = (u16*)(ws + OFF_WSTG);
    u16* enc = (u16*)(ws + OFF_ENC);

    // zero h0,h1,c + barrier counters (contiguous [0, 786944))
    k_zero<<<3074, 256, 0, stream>>>(ws, 786944);
    k_hw_all<<<T, 256, 0, stream>>>(dist, rb, cog, mask, domain, w_all, wmax_all);
    k_wconv<<<dim3(16, 16, 18), 256, 0, stream>>>(W_ih, W_hh, Wstg);
    k_seqstg<<<dim3(16, T + 1), 256, 0, stream>>>(seq, maxval, minval, seqstg);

    // whole recurrence (64 encoder steps + 1 decoder step) in one launch
    k_recur<<<256, 256, 0, stream>>>(seqstg, Wstg, w_all, wmax_all, b_ih, b_hh,
                                     h0buf, h1buf, c, enc, whstg, bar);

    // final h is in h0buf (t=64 writes buf[0])
    k_attn<<<B * V, 256, 0, stream>>>(enc, h0buf, mask, ctx);
    k_soft<<<dim3(16, 16), 256, 0, stream>>>(ctx, h0buf, soft_W, soft_b, hsoft);
    k_out<<<B * V, 64, 0, stream>>>(hsoft, out_W, out_b, (float*)d_out);
}

// Round 7
// 937.001 us; speedup vs baseline: 3.5283x; 1.1908x over previous
//
#include <hip/hip_runtime.h>
#include <math.h>

#define B 32
#define V 16
#define T 64
#define F 64
#define H 512
#define NB 36
#define G4H 2048

typedef unsigned short u16;
typedef unsigned long long ull;
typedef __attribute__((ext_vector_type(8))) short bf16x8;
typedef __attribute__((ext_vector_type(4))) float f32x4;

// workspace offsets (float units)
#define OFF_H0     0           // 262144
#define OFF_H1     262144      // 262144
#define OFF_C      524288      // 262144
#define OFF_CNT    786432      // 1024 (barrier counters, 64B-padded)
#define OFF_WALL   787456      // 524288 fp32 w_all; ctx/hsoft alias (dead after k_recur)
#define OFF_CTX    787456      // 262144 (alias)
#define OFF_HSOFT  1049600     // 262144 (alias)
#define OFF_WMAX   1311744     // 64
#define OFF_WHSTG  1311808     // 262144 fl = 2 parities x 262144 u16 (wh, A-frag bf16)
#define OFF_SEQSTG 1573952     // 1064960 fl = 2129920 u16 (seq all t + denorm t=64, A-frag)
#define OFF_WSTG   2638912     // 9437184 fl (weights, B-frag bf16)
#define OFF_ENC    12076096    // 8388608 fl = 16777216 u16 (enc bf16)
// total 20,464,704 fl = 81.9 MB

#define WHP 262144   // u16 per whstg parity
#define WLDS_BYTES 147456  // 144 KB per-block weight slice (dynamic LDS)

__device__ __forceinline__ float sigmoidf_(float x) { return 1.0f / (1.0f + __expf(-x)); }

__device__ __forceinline__ u16 f2bf(float f) {  // RNE fp32->bf16
    union { float f; unsigned u; } x; x.f = f;
    unsigned r = x.u + 0x7FFF + ((x.u >> 16) & 1);
    return (u16)(r >> 16);
}
__device__ __forceinline__ float bf2f(u16 u) {
    union { unsigned i; float f; } x; x.i = ((unsigned)u) << 16;
    return x.f;
}
__device__ __forceinline__ f32x4 mfma16(bf16x8 a, bf16x8 b, f32x4 c) {
    return __builtin_amdgcn_mfma_f32_16x16x32_bf16(a, b, c, 0, 0, 0);
}
__device__ __forceinline__ bf16x8 mk_bf16x8(ull lo, ull hi) {
    union { ull u[2]; bf16x8 v; } x; x.u[0] = lo; x.u[1] = hi; return x.v;
}
__device__ __forceinline__ bf16x8 mk_bf16x8q(uint4 q) {
    union { uint4 q; bf16x8 v; } x; x.q = q; return x.v;
}

// device-scope coherent accesses (serviced at coherence point; no fences)
__device__ __forceinline__ ull ld_agent(const ull* p) {
    return __hip_atomic_load((ull*)p, __ATOMIC_RELAXED, __HIP_MEMORY_SCOPE_AGENT);
}
__device__ __forceinline__ void st_agent(ull* p, ull x) {
    __hip_atomic_store(p, x, __ATOMIC_RELAXED, __HIP_MEMORY_SCOPE_AGENT);
}
__device__ __forceinline__ void st_agent_f(float* p, float x) {
    __hip_atomic_store(p, x, __ATOMIC_RELAXED, __HIP_MEMORY_SCOPE_AGENT);
}

// 16-way group barrier (validated R5/R6)
__device__ __forceinline__ void bar_sync(unsigned* cnt, unsigned target) {
    __syncthreads();
    if (threadIdx.x == 0) {
        __builtin_amdgcn_s_waitcnt(0);
        __hip_atomic_fetch_add(cnt, 1u, __ATOMIC_RELAXED, __HIP_MEMORY_SCOPE_AGENT);
        while (__hip_atomic_load(cnt, __ATOMIC_RELAXED, __HIP_MEMORY_SCOPE_AGENT) < target)
            __builtin_amdgcn_s_sleep(1);
    }
    __syncthreads();
}

// 2-level grid barrier: 16 group counters (16 blocks each) + top counter.
// t1 = step ordinal (monotone); group counter target t1*16, top target t1*16.
__device__ __forceinline__ void gbar_grid(unsigned* grp, unsigned* top, unsigned t1) {
    __syncthreads();
    if (threadIdx.x == 0) {
        __builtin_amdgcn_s_waitcnt(0);
        unsigned old = __hip_atomic_fetch_add(grp, 1u, __ATOMIC_RELAXED, __HIP_MEMORY_SCOPE_AGENT);
        if (old == t1 * 16u - 1u)  // last arriver of this group this step
            __hip_atomic_fetch_add(top, 1u, __ATOMIC_RELAXED, __HIP_MEMORY_SCOPE_AGENT);
        while (__hip_atomic_load(top, __ATOMIC_RELAXED, __HIP_MEMORY_SCOPE_AGENT) < t1 * 16u)
            __builtin_amdgcn_s_sleep(1);
    }
    __syncthreads();
}

// ---------------------------------------------------------------------------
__global__ void k_zero(float* __restrict__ p, int n) {
    int i = blockIdx.x * blockDim.x + threadIdx.x;
    if (i < n) p[i] = 0.0f;
}

// ---------------------------------------------------------------------------
// hardwired weights for all t: w_all[t][b][i][j] fp32 + wmax_all[t]
__global__ __launch_bounds__(256) void k_hw_all(
    const float* __restrict__ dist, const int* __restrict__ rb,
    const int* __restrict__ cog, const float* __restrict__ mask,
    const float* __restrict__ domain, float* __restrict__ w_all,
    float* __restrict__ wmax_all) {
    int t = blockIdx.x;
    __shared__ float red[256];
    int tid = threadIdx.x;
    float lmax = 0.0f;
    for (int idx = tid; idx < B * V * V; idx += 256) {
        int b = idx >> 8;
        int rem = idx & 255;
        int i = rem >> 4, j = rem & 15;
        int base = ((b * V + i) * T + t) * V + j;
        float val = domain[cog[base] * NB + rb[base]] - dist[base];
        val = val > 0.0f ? val : 0.0f;
        val *= mask[(b * V + i) * T + t] * mask[(b * V + j) * T + t];
        w_all[t * (B * V * V) + idx] = val;
        lmax = fmaxf(lmax, val);
    }
    red[tid] = lmax;
    __syncthreads();
    for (int s = 128; s > 0; s >>= 1) {
        if (tid < s) red[tid] = fmaxf(red[tid], red[tid + s]);
        __syncthreads();
    }
    if (tid == 0) wmax_all[t] = red[0];
}

// ---------------------------------------------------------------------------
// One-time: W_ih||W_hh (fp32, K-minor) -> bf16 B-fragment layout
// Wstg[v][hk16][ks18][nt8][lane64][8]; nt=g*2+hh; col=g*512+hk*32+hh*16+(lane&15)
__global__ __launch_bounds__(256) void k_wconv(
    const float* __restrict__ W_ih, const float* __restrict__ W_hh,
    u16* __restrict__ Wstg) {
    int v = blockIdx.x, hk = blockIdx.y, ks = blockIdx.z;
    int tid = threadIdx.x;
#pragma unroll
    for (int s = 0; s < 2; ++s) {
        int slot = tid + s * 256;
        int nt = slot >> 6, lane = slot & 63;
        int g = nt >> 1, hh = nt & 1;
        int col = g * H + hk * 32 + hh * 16 + (lane & 15);
        int k = ks * 32 + ((lane >> 4) << 3);
        const float* src = (k < F) ? &W_ih[(v * G4H + col) * F + k]
                                   : &W_hh[(v * G4H + col) * H + (k - F)];
        float4 x0 = *(const float4*)src;
        float4 x1 = *(const float4*)(src + 4);
        union { u16 u[8]; uint4 q; } pk;
        pk.u[0] = f2bf(x0.x); pk.u[1] = f2bf(x0.y); pk.u[2] = f2bf(x0.z); pk.u[3] = f2bf(x0.w);
        pk.u[4] = f2bf(x1.x); pk.u[5] = f2bf(x1.y); pk.u[6] = f2bf(x1.z); pk.u[7] = f2bf(x1.w);
        *(uint4*)&Wstg[(size_t)((((v * 16 + hk) * 18 + ks) * 8 + nt) * 64 + lane) * 8] = pk.q;
    }
}

// ---------------------------------------------------------------------------
// One-time: pack seq for all t (t=64 = denormalized last input) into A-frag bf16:
// seqstg[t][v][mt2][ks2][lane64][8]
__global__ __launch_bounds__(256) void k_seqstg(
    const float* __restrict__ seq, const float* __restrict__ maxval,
    const float* __restrict__ minval, u16* __restrict__ seqstg) {
    int v = blockIdx.x, t = blockIdx.y;  // t in 0..64
    int tid = threadIdx.x;
    int mt = tid >> 7, ks = (tid >> 6) & 1, lane = tid & 63;
    int b = mt * 16 + (lane & 15);
    int f = ks * 32 + ((lane >> 4) << 3);
    union { u16 u[8]; uint4 q; } pk;
    if (t < T) {
        const float* sp = &seq[((b * V + v) * T + t) * F + f];
        float4 x0 = *(const float4*)sp, x1 = *(const float4*)(sp + 4);
        pk.u[0] = f2bf(x0.x); pk.u[1] = f2bf(x0.y); pk.u[2] = f2bf(x0.z); pk.u[3] = f2bf(x0.w);
        pk.u[4] = f2bf(x1.x); pk.u[5] = f2bf(x1.y); pk.u[6] = f2bf(x1.z); pk.u[7] = f2bf(x1.w);
    } else {
        const float* sp = &seq[((b * V + v) * T + (T - 1)) * F + f];
        float4 x0 = *(const float4*)sp, x1 = *(const float4*)(sp + 4);
        float4 mx0 = *(const float4*)&maxval[b * F + f], mx1 = *(const float4*)&maxval[b * F + f + 4];
        float4 mn0 = *(const float4*)&minval[b * F + f], mn1 = *(const float4*)&minval[b * F + f + 4];
        pk.u[0] = f2bf(x0.x * (mx0.x - mn0.x) + mn0.x);
        pk.u[1] = f2bf(x0.y * (mx0.y - mn0.y) + mn0.y);
        pk.u[2] = f2bf(x0.z * (mx0.z - mn0.z) + mn0.z);
        pk.u[3] = f2bf(x0.w * (mx0.w - mn0.w) + mn0.w);
        pk.u[4] = f2bf(x1.x * (mx1.x - mn1.x) + mn1.x);
        pk.u[5] = f2bf(x1.y * (mx1.y - mn1.y) + mn1.y);
        pk.u[6] = f2bf(x1.z * (mx1.z - mn1.z) + mn1.z);
        pk.u[7] = f2bf(x1.w * (mx1.w - mn1.w) + mn1.w);
    }
    *(uint4*)&seqstg[(((size_t)(t * 16 + v)) * 4 + mt * 2 + ks) * 512 + lane * 8] = pk.q;
}

// ---------------------------------------------------------------------------
// Persistent recurrence R7: weight slice pinned in LDS (144 KB, whole kernel);
// phase A repartitioned to (b-pair p=bid&15, col-slice hkA=bid>>4): each h elem
// read once (1 MB/step, was 16 MB).  B(v=bid&15, hk=bid>>4) unchanged math.
// Barriers: grid (2-level) after A (B needs all A writes); 16-way hk-family
// after B (A(t+1) reads only its hk-slice of h).  WAR on whstg covered by
// parity + barrier transitivity.
__global__ __launch_bounds__(256) void k_recur(
    const u16* __restrict__ seqstg, const u16* __restrict__ Wstg,
    const float* __restrict__ w_all, const float* __restrict__ wmax_all,
    const float* __restrict__ b_ih, const float* __restrict__ b_hh,
    float* __restrict__ h0buf, float* __restrict__ h1buf,
    float* __restrict__ c, u16* __restrict__ enc, u16* __restrict__ whstg,
    unsigned* __restrict__ bar) {
    extern __shared__ u16 Wlds[];          // 144 KB weight slice
    __shared__ float hstage[2][16][33];    // 4.1 KB  [bl][j][col+pad]
    __shared__ float swA[2 * 16 * 16];     // 2 KB    w rows for this b-pair

    int bid = blockIdx.x;
    int v = bid & 15, hk = bid >> 4;       // B roles
    int p = bid & 15, hkA = bid >> 4;      // A roles
    int tid = threadIdx.x;

    // ---- one-time: pin weight slice in LDS
    {
        const uint4* wsrc = (const uint4*)(Wstg + (size_t)((v * 16 + hk) * 18) * 4096);
        uint4* wdst = (uint4*)Wlds;
        for (int i = tid; i < 9216; i += 256) wdst[i] = wsrc[i];
    }

    int lane = tid & 63, wvi = tid >> 6;
    int mtw = wvi & 1, hh = wvi >> 1;
    int col = hk * 32 + hh * 16 + (lane & 15);
    int q4 = (lane >> 4) << 2;
    float bi = b_ih[v * G4H + col] + b_hh[v * G4H + col];
    float bf_ = b_ih[v * G4H + H + col] + b_hh[v * G4H + H + col];
    float bg_ = b_ih[v * G4H + 2 * H + col] + b_hh[v * G4H + 2 * H + col];
    float bo = b_ih[v * G4H + 3 * H + col] + b_hh[v * G4H + 3 * H + col];

    unsigned* hkcnt = bar + hk * 16;             // 16-way family counter
    unsigned* g1grp = bar + (16 + hk) * 16;      // grid barrier level-1
    unsigned* g1top = bar + 32 * 16;             // grid barrier top
    unsigned htarget = 0;

    // phase-A thread maps
    int a_bl = tid >> 7;                 // load map: (bl, j, q)
    int a_j = (tid >> 3) & 15;
    int a_q = tid & 7;
    int c_bl = tid >> 7;                 // compute map: (bl, v', colq)
    int c_v = (tid >> 3) & 15;
    int c_cq = tid & 7;

    __syncthreads();  // W-LDS fill complete

    for (int t = 0; t <= T; ++t) {
        int par = t & 1;
        int tm = t < T ? t : (T - 1);
        const float* hin = (t & 1) ? h0buf : h1buf;
        float* hout = (t & 1) ? h1buf : h0buf;

        // ---- phase A: stage h (distinct 4 KB) + w rows, then compute wh
        {
            const ull* hq = (const ull*)&hin[((2 * p + a_bl) * V + a_j) * H + hkA * 32 + a_q * 4];
            ull lo = ld_agent(hq), hi = ld_agent(hq + 1);
            for (int i = tid; i < 512; i += 256)
                swA[i] = w_all[(size_t)tm * (B * V * V) + p * 512 + i];
            union { ull u; float f[2]; } u0, u1;
            u0.u = lo; u1.u = hi;
            hstage[a_bl][a_j][a_q * 4 + 0] = u0.f[0];
            hstage[a_bl][a_j][a_q * 4 + 1] = u0.f[1];
            hstage[a_bl][a_j][a_q * 4 + 2] = u1.f[0];
            hstage[a_bl][a_j][a_q * 4 + 3] = u1.f[1];
        }
        __syncthreads();
        {
            float inv = 1.0f / wmax_all[tm];
            float a0 = 0.f, a1 = 0.f, a2 = 0.f, a3 = 0.f;
#pragma unroll
            for (int j = 0; j < 16; ++j) {
                float wj = swA[(c_bl * 16 + c_v) * 16 + j];
                a0 += wj * hstage[c_bl][j][c_cq * 4 + 0];
                a1 += wj * hstage[c_bl][j][c_cq * 4 + 1];
                a2 += wj * hstage[c_bl][j][c_cq * 4 + 2];
                a3 += wj * hstage[c_bl][j][c_cq * 4 + 3];
            }
            union { u16 u[4]; ull q; } pk;
            pk.u[0] = f2bf(a0 * inv); pk.u[1] = f2bf(a1 * inv);
            pk.u[2] = f2bf(a2 * inv); pk.u[3] = f2bf(a3 * inv);
            int b = 2 * p + c_bl;
            int mt = b >> 4;
            int fl = (c_cq >> 1) * 16 + (b & 15);   // frag lane
            int half = c_cq & 1;
            st_agent((ull*)&whstg[par * WHP + ((((c_v * 2 + mt) * 16 + hkA) * 64 + fl) * 8 + half * 4)],
                     pk.q);
        }
        __syncthreads();  // hstage/swA WAR before next use (and pre-barrier drain)

        // ---- grid barrier: all wh writes visible
        gbar_grid(g1grp, g1top, (unsigned)(t + 1));

        // ---- phase B: A-fragments -> registers (max MLP), W from LDS
        bf16x8 afr[18];
        {
            uint4 s0 = *(const uint4*)&seqstg[(((size_t)(t * 16 + v)) * 4 + mtw * 2 + 0) * 512 + lane * 8];
            uint4 s1 = *(const uint4*)&seqstg[(((size_t)(t * 16 + v)) * 4 + mtw * 2 + 1) * 512 + lane * 8];
            afr[0] = mk_bf16x8q(s0);
            afr[1] = mk_bf16x8q(s1);
#pragma unroll
            for (int ksw = 0; ksw < 16; ++ksw) {
                const ull* src = (const ull*)&whstg[par * WHP + (((v * 2 + mtw) * 16 + ksw) * 64 + lane) * 8];
                ull lo = ld_agent(src), hi = ld_agent(src + 1);
                afr[2 + ksw] = mk_bf16x8(lo, hi);
            }
        }

        f32x4 acc[4];
#pragma unroll
        for (int g = 0; g < 4; ++g) { acc[g][0] = 0.f; acc[g][1] = 0.f; acc[g][2] = 0.f; acc[g][3] = 0.f; }

#pragma unroll
        for (int ks = 0; ks < 18; ++ks) {
#pragma unroll
            for (int g = 0; g < 4; ++g) {
                bf16x8 wfr = *(const bf16x8*)&Wlds[(ks * 8 + (g * 2 + hh)) * 512 + lane * 8];
                acc[g] = mfma16(afr[ks], wfr, acc[g]);
            }
        }

        // ---- epilogue: c (block-private, cached), h (sc1), enc (cached)
#pragma unroll
        for (int r = 0; r < 4; ++r) {
            int b = mtw * 16 + q4 + r;
            float gi = acc[0][r] + bi;
            float gf = acc[1][r] + bf_;
            float gg = acc[2][r] + bg_;
            float go = acc[3][r] + bo;
            int idx = (b * V + v) * H + col;
            float cn = sigmoidf_(gf) * c[idx] + sigmoidf_(gi) * tanhf(gg);
            float hn = sigmoidf_(go) * tanhf(cn);
            c[idx] = cn;
            st_agent_f(&hout[idx], hn);
            if (t < T) enc[((size_t)(b * V + v) * T + t) * H + col] = f2bf(hn);
        }

        // ---- hk-family barrier: h hk-slice ready for next step's phase A
        if (t < T) {
            htarget += 16;
            bar_sync(hkcnt, htarget);
        }
    }
}

// ---------------------------------------------------------------------------
// soft attention over bf16 enc.  block=(b,v)
__global__ __launch_bounds__(256) void k_attn(
    const u16* __restrict__ enc, const float* __restrict__ h,
    const float* __restrict__ mask, float* __restrict__ ctx) {
    int bid = blockIdx.x;
    int b = bid >> 4, v = bid & 15;
    int tid = threadIdx.x;
    int wave = tid >> 6, lane = tid & 63;
    __shared__ float hs[H];
    __shared__ float sc[T];
    __shared__ float al[T];
    const u16* encbase = enc + (size_t)((b * V + v) * T) * H;
    const float* hb = h + (b * V + v) * H;
    for (int i = tid; i < H; i += 256) hs[i] = hb[i];
    __syncthreads();
    for (int tt = wave; tt < T; tt += 4) {
        const u16* e = encbase + tt * H;
        float p = 0.0f;
#pragma unroll
        for (int ii = 0; ii < 8; ++ii) p += bf2f(e[ii * 64 + lane]) * hs[ii * 64 + lane];
        for (int off = 32; off; off >>= 1) p += __shfl_down(p, off, 64);
        if (lane == 0) sc[tt] = p;
    }
    __syncthreads();
    if (tid < 64) {
        float m_t = mask[(b * V + v) * T + tid];
        float s = sc[tid] * m_t;
        float mx = s;
        for (int off = 32; off; off >>= 1) mx = fmaxf(mx, __shfl_xor(mx, off, 64));
        float e = __expf(s - mx);
        float sum = e;
        for (int off = 32; off; off >>= 1) sum += __shfl_xor(sum, off, 64);
        al[tid] = e / sum;
    }
    __syncthreads();
    for (int hh = tid; hh < H; hh += 256) {
        float a = 0.0f;
        for (int tt = 0; tt < T; ++tt) a += al[tt] * bf2f(encbase[tt * H + hh]);
        ctx[(b * V + v) * H + hh] = a;
    }
}

// ---------------------------------------------------------------------------
// per-vessel soft linear (torch stack/view reinterleave).  grid (16,16), 32-col tiles.
__global__ __launch_bounds__(256) void k_soft(
    const float* __restrict__ ctx, const float* __restrict__ hdec,
    const float* __restrict__ soft_W, const float* __restrict__ soft_b,
    float* __restrict__ hsoft) {
    int v = blockIdx.x;
    int h0 = blockIdx.y * 32;
    int tid = threadIdx.x;
    int cg = tid & 31, rg = tid >> 5;
    __shared__ float sA[32][36];
    __shared__ float sW2[32][36];
    float* sAf = &sA[0][0];
    float* sWf = &sW2[0][0];
    float acc[4] = {0.f, 0.f, 0.f, 0.f};
    int arow = tid >> 3, akq = tid & 7;
    float4 areg, wreg;

    {
        int k = akq * 4;
        const float* src = (arow < 16) ? ctx : hdec;
        int bsrc = 2 * (arow & 15) + (k >= H ? 1 : 0);
        areg = *(const float4*)&src[(bsrc * V + v) * H + (k & (H - 1))];
        wreg = *(const float4*)&soft_W[(v * H + h0 + arow) * (2 * H) + k];
    }
    for (int kc = 0; kc < 2 * H; kc += 32) {
        __syncthreads();
        *(float4*)&sAf[arow * 36 + akq * 4] = areg;
        *(float4*)&sWf[arow * 36 + akq * 4] = wreg;
        __syncthreads();
        if (kc + 32 < 2 * H) {
            int k = kc + 32 + akq * 4;
            const float* src = (arow < 16) ? ctx : hdec;
            int bsrc = 2 * (arow & 15) + (k >= H ? 1 : 0);
            areg = *(const float4*)&src[(bsrc * V + v) * H + (k & (H - 1))];
            wreg = *(const float4*)&soft_W[(v * H + h0 + arow) * (2 * H) + kc + 32 + akq * 4];
        }
#pragma unroll
        for (int k4 = 0; k4 < 8; ++k4) {
            float4 wv = *(const float4*)&sWf[cg * 36 + k4 * 4];
            float4 a0 = *(const float4*)&sAf[(rg * 4 + 0) * 36 + k4 * 4];
            float4 a1 = *(const float4*)&sAf[(rg * 4 + 1) * 36 + k4 * 4];
            float4 a2 = *(const float4*)&sAf[(rg * 4 + 2) * 36 + k4 * 4];
            float4 a3 = *(const float4*)&sAf[(rg * 4 + 3) * 36 + k4 * 4];
            acc[0] += a0.x * wv.x + a0.y * wv.y + a0.z * wv.z + a0.w * wv.w;
            acc[1] += a1.x * wv.x + a1.y * wv.y + a1.z * wv.z + a1.w * wv.w;
            acc[2] += a2.x * wv.x + a2.y * wv.y + a2.z * wv.z + a2.w * wv.w;
            acc[3] += a3.x * wv.x + a3.y * wv.y + a3.z * wv.z + a3.w * wv.w;
        }
    }
    float bb = soft_b[v * H + h0 + cg];
#pragma unroll
    for (int r = 0; r < 4; ++r) {
        int row = rg * 4 + r;
        hsoft[(row * V + v) * H + h0 + cg] = tanhf(acc[r] + bb);
    }
}

// ---------------------------------------------------------------------------
__global__ __launch_bounds__(64) void k_out(
    const float* __restrict__ hsoft, const float* __restrict__ outW,
    const float* __restrict__ outb, float* __restrict__ out) {
    int bid = blockIdx.x;
    int b = bid >> 4, v = bid & 15;
    int lane = threadIdx.x;
    const float* hb = hsoft + (b * V + v) * H;
    float p[4] = {0.0f, 0.0f, 0.0f, 0.0f};
#pragma unroll
    for (int ii = 0; ii < 8; ++ii) {
        float hv = hb[ii * 64 + lane];
#pragma unroll
        for (int o = 0; o < 4; ++o) p[o] += hv * outW[o * H + ii * 64 + lane];
    }
#pragma unroll
    for (int o = 0; o < 4; ++o) {
        float s = p[o];
        for (int off = 32; off; off >>= 1) s += __shfl_down(s, off, 64);
        if (lane == 0) {
            float val = s + outb[o];
            out[(b * V + v) * 4 + o] = val > 0.0f ? val : 0.0f;
        }
    }
}

// ---------------------------------------------------------------------------
extern "C" void kernel_launch(void* const* d_in, const int* in_sizes, int n_in,
                              void* d_out, int out_size, void* d_ws, size_t ws_size,
                              hipStream_t stream) {
    const float* seq = (const float*)d_in[0];
    const float* dist = (const float*)d_in[1];
    const int* rb = (const int*)d_in[2];
    const int* cog = (const int*)d_in[3];
    const float* mask = (const float*)d_in[4];
    const float* maxval = (const float*)d_in[5];
    const float* minval = (const float*)d_in[6];
    const float* W_ih = (const float*)d_in[7];
    const float* W_hh = (const float*)d_in[8];
    const float* b_ih = (const float*)d_in[9];
    const float* b_hh = (const float*)d_in[10];
    const float* domain = (const float*)d_in[11];
    const float* soft_W = (const float*)d_in[12];
    const float* soft_b = (const float*)d_in[13];
    const float* out_W = (const float*)d_in[14];
    const float* out_b = (const float*)d_in[15];

    float* ws = (float*)d_ws;
    float* h0buf = ws + OFF_H0;
    float* h1buf = ws + OFF_H1;
    float* c = ws + OFF_C;
    unsigned* bar = (unsigned*)(ws + OFF_CNT);
    float* w_all = ws + OFF_WALL;
    float* ctx = ws + OFF_CTX;      // alias (w_all dead after k_recur)
    float* hsoft = ws + OFF_HSOFT;  // alias
    float* wmax_all = ws + OFF_WMAX;
    u16* whstg = (u16*)(ws + OFF_WHSTG);
    u16* seqstg = (u16*)(ws + OFF_SEQSTG);
    u16* Wstg = (u16*)(ws + OFF_WSTG);
    u16* enc = (u16*)(ws + OFF_ENC);

    // allow >64 KB dynamic LDS for k_recur (idempotent; capture-safe host call)
    (void)hipFuncSetAttribute((const void*)k_recur,
                              hipFuncAttributeMaxDynamicSharedMemorySize, WLDS_BYTES);

    // zero h0,h1,c + barrier counters (contiguous [0, 787456))
    k_zero<<<3076, 256, 0, stream>>>(ws, 787456);
    k_hw_all<<<T, 256, 0, stream>>>(dist, rb, cog, mask, domain, w_all, wmax_all);
    k_wconv<<<dim3(16, 16, 18), 256, 0, stream>>>(W_ih, W_hh, Wstg);
    k_seqstg<<<dim3(16, T + 1), 256, 0, stream>>>(seq, maxval, minval, seqstg);

    // whole recurrence (64 encoder steps + 1 decoder step) in one launch
    k_recur<<<256, 256, WLDS_BYTES, stream>>>(seqstg, Wstg, w_all, wmax_all,
                                              b_ih, b_hh, h0buf, h1buf, c, enc,
                                              whstg, bar);

    // final h is in h0buf (t=64 writes buf[0])
    k_attn<<<B * V, 256, 0, stream>>>(enc, h0buf, mask, ctx);
    k_soft<<<dim3(16, 16), 256, 0, stream>>>(ctx, h0buf, soft_W, soft_b, hsoft);
    k_out<<<B * V, 64, 0, stream>>>(hsoft, out_W, out_b, (float*)d_out);
}